// Round 1
// baseline (690.146 us; speedup 1.0000x reference)
//
#include <hip/hip_runtime.h>

constexpr int B = 128, C = 256;
constexpr float EPS = 1e-5f;

// Fused: depthwise 3x3 VALID conv -> BN1 -> ReLU6 -> 1x1 conv (GEMM) -> +bias -> BN2
// GEMM view: out[co, n] = sum_ci W[co,ci] * X[ci, n],  n = b*P + p (p = spatial)
// Block: 64 co x 64 n tile, 256 threads, 4x4 microtile per thread, K-chunks of 16.
// X-tile elements are computed on the fly (dwconv+BN1+ReLU6 fused into staging).
template<int IN_H>
__global__ __launch_bounds__(256)
void branch_kernel(const float* __restrict__ in,     // (B,C,IN_H,IN_H)
                   const float* __restrict__ dw_w,   // (C,1,3,3)
                   const float* __restrict__ bn1,    // (4,C): g,b,m,v
                   const float* __restrict__ pw_w,   // (C,C)
                   const float* __restrict__ pw_b,   // (C)
                   const float* __restrict__ bn2,    // (4,C)
                   float* __restrict__ out)          // (B,C,OUT_H,OUT_H)
{
    constexpr int OUT_H = IN_H - 2;
    constexpr int P = OUT_H * OUT_H;

    const int n0  = blockIdx.x * 64;
    const int co0 = blockIdx.y * 64;
    const int tid = threadIdx.x;
    const int tx = tid & 15;   // n-group
    const int ty = tid >> 4;   // co-group

    __shared__ __align__(16) float Ws[16][64];   // [kk][co_local]
    __shared__ __align__(16) float Xs[16][64];   // [kk][n_local]

    float acc[4][4] = {};

    for (int k0 = 0; k0 < C; k0 += 16) {
        // ---- W tile: lanes -> co_local consecutive (stride-1 LDS writes, L1 line reuse on global)
        #pragma unroll
        for (int e = 0; e < 4; e++) {
            int idx = e * 256 + tid;
            int m = idx & 63, kk = idx >> 6;
            Ws[kk][m] = pw_w[(co0 + m) * C + (k0 + kk)];
        }
        // ---- X tile: fused dwconv 3x3 + BN1 + ReLU6
        #pragma unroll
        for (int e = 0; e < 4; e++) {
            int idx = e * 256 + tid;
            int nn = idx & 63, kk = idx >> 6;
            int ci = k0 + kk;
            int n  = n0 + nn;
            int b  = n / P, p = n - b * P;
            int oh = p / OUT_H, ow = p - oh * OUT_H;
            const float* ip = in + (((size_t)b * C + ci) * IN_H + oh) * IN_H + ow;
            const float* wp = dw_w + ci * 9;
            float s = 0.f;
            #pragma unroll
            for (int dy = 0; dy < 3; dy++)
                #pragma unroll
                for (int dx = 0; dx < 3; dx++)
                    s = fmaf(ip[dy * IN_H + dx], wp[dy * 3 + dx], s);
            float inv = bn1[ci] * rsqrtf(bn1[3 * C + ci] + EPS);
            float y = s * inv + (bn1[C + ci] - bn1[2 * C + ci] * inv);
            Xs[kk][nn] = fminf(fmaxf(y, 0.f), 6.f);
        }
        __syncthreads();

        #pragma unroll
        for (int kk = 0; kk < 16; kk++) {
            float4 av = *reinterpret_cast<const float4*>(&Ws[kk][ty * 4]); // broadcast (16 lanes same addr)
            float4 bv = *reinterpret_cast<const float4*>(&Xs[kk][tx * 4]); // 2-way aliasing = free
            float a[4]  = {av.x, av.y, av.z, av.w};
            float bb[4] = {bv.x, bv.y, bv.z, bv.w};
            #pragma unroll
            for (int i = 0; i < 4; i++)
                #pragma unroll
                for (int j = 0; j < 4; j++)
                    acc[i][j] = fmaf(a[i], bb[j], acc[i][j]);
        }
        __syncthreads();
    }

    // ---- epilogue: (acc + pw_b) -> BN2 -> store
    #pragma unroll
    for (int i = 0; i < 4; i++) {
        int co = co0 + ty * 4 + i;
        float inv = bn2[co] * rsqrtf(bn2[3 * C + co] + EPS);
        float sh  = (bn2[C + co] - bn2[2 * C + co] * inv) + pw_b[co] * inv;
        int n = n0 + tx * 4;
        #pragma unroll
        for (int j = 0; j < 4; j++) {
            int nj = n + j;
            int bj = nj / P, pj = nj - bj * P;
            out[((size_t)bj * C + co) * P + pj] = acc[i][j] * inv + sh;
        }
    }
}

// Depthwise cross-correlation: out[b,c,:,:] = s[b,c] (29x29) corr k[b,c] (5x5) -> 25x25
__global__ __launch_bounds__(256)
void xcorr_kernel(const float* __restrict__ s,   // (B,C,29,29)
                  const float* __restrict__ k,   // (B,C,5,5)
                  float* __restrict__ out)       // (B,C,25,25)
{
    const int bc = blockIdx.x;
    __shared__ float ss[841];
    __shared__ float ks[25];
    const float* sp = s + (size_t)bc * 841;
    const float* kp = k + (size_t)bc * 25;
    const int tid = threadIdx.x;
    for (int i = tid; i < 841; i += 256) ss[i] = sp[i];
    if (tid < 25) ks[tid] = kp[tid];
    __syncthreads();

    float* op = out + (size_t)bc * 625;
    for (int p = tid; p < 625; p += 256) {
        int oh = p / 25, ow = p - (p / 25) * 25;
        float acc = 0.f;
        #pragma unroll
        for (int i = 0; i < 5; i++)
            #pragma unroll
            for (int j = 0; j < 5; j++)
                acc = fmaf(ss[(oh + i) * 29 + ow + j], ks[i * 5 + j], acc);
        op[p] = acc;
    }
}

extern "C" void kernel_launch(void* const* d_in, const int* in_sizes, int n_in,
                              void* d_out, int out_size, void* d_ws, size_t ws_size,
                              hipStream_t stream) {
    const float* kernel = (const float*)d_in[0];
    const float* search = (const float*)d_in[1];
    const float* k_dw_w = (const float*)d_in[2];
    const float* k_bn1  = (const float*)d_in[3];
    const float* k_pw_w = (const float*)d_in[4];
    const float* k_pw_b = (const float*)d_in[5];
    const float* k_bn2  = (const float*)d_in[6];
    const float* s_dw_w = (const float*)d_in[7];
    const float* s_bn1  = (const float*)d_in[8];
    const float* s_pw_w = (const float*)d_in[9];
    const float* s_pw_b = (const float*)d_in[10];
    const float* s_bn2  = (const float*)d_in[11];

    float* s_buf = (float*)d_ws;                       // (B,C,29,29) = 110.2 MB
    float* k_buf = s_buf + (size_t)B * C * 29 * 29;    // (B,C,5,5)   =   3.3 MB

    dim3 blk(256);
    // kernel branch: N = 128*25 = 3200 -> 50 n-tiles; co-tiles = 4
    branch_kernel<7><<<dim3(50, 4), blk, 0, stream>>>(
        kernel, k_dw_w, k_bn1, k_pw_w, k_pw_b, k_bn2, k_buf);
    // search branch: N = 128*841 = 107648 -> 1682 n-tiles
    branch_kernel<31><<<dim3(1682, 4), blk, 0, stream>>>(
        search, s_dw_w, s_bn1, s_pw_w, s_pw_b, s_bn2, s_buf);
    // xcorr: one block per (b,c)
    xcorr_kernel<<<dim3(B * C), blk, 0, stream>>>(s_buf, k_buf, (float*)d_out);
}

// Round 2
// 368.277 us; speedup vs baseline: 1.8740x; 1.8740x over previous
//
#include <hip/hip_runtime.h>

constexpr int B = 128, C = 256;
constexpr float EPS = 1e-5f;

typedef unsigned short u16;
typedef short short8 __attribute__((ext_vector_type(8)));
typedef u16 u16x8 __attribute__((ext_vector_type(8)));
typedef float f32x4 __attribute__((ext_vector_type(4)));

__device__ __forceinline__ u16 bf16_rne(float x) {
    unsigned u = __builtin_bit_cast(unsigned, x);
    return (u16)((u + 0x7FFFu + ((u >> 16) & 1u)) >> 16);
}

#define GLOAD16(g, l)                                                              \
    __builtin_amdgcn_global_load_lds(                                              \
        (const __attribute__((address_space(1))) unsigned int*)(g),                \
        (__attribute__((address_space(3))) unsigned int*)(l), 16, 0, 0)

// ---------------------------------------------------------------------------
// Pass 1: depthwise 3x3 VALID + BN1 + ReLU6 -> X3[n][512] bf16 rows
//         (cols 0..255 = hi(x), 256..511 = lo(x)); LDS transpose for
//         coalesced 1KB row writes.
// ---------------------------------------------------------------------------
template<int IN_H>
__global__ __launch_bounds__(256)
void dw_pass(const float* __restrict__ in, const float* __restrict__ dw_w,
             const float* __restrict__ bn1, u16* __restrict__ X3) {
    constexpr int OUT_H = IN_H - 2, P = OUT_H * OUT_H, IHW = IN_H * IN_H;
    __shared__ u16 XS[64][520];   // row n' x (256 hi | 256 lo), stride 1040 B
    const int tid = threadIdx.x;
    const int ln = tid & 63, w = tid >> 6;
    const int n = blockIdx.x * 64 + ln;
    const int b = n / P, p = n - b * P;
    const int oh = p / OUT_H, ow = p - oh * OUT_H;
    const float* ip0 = in + ((size_t)b * C * IN_H + oh) * IN_H + ow;

    #pragma unroll 2
    for (int ci = w; ci < C; ci += 4) {
        const float* ip = ip0 + (size_t)ci * IHW;
        const float* wp = dw_w + ci * 9;
        float s = 0.f;
        #pragma unroll
        for (int dy = 0; dy < 3; dy++)
            #pragma unroll
            for (int dx = 0; dx < 3; dx++)
                s = fmaf(ip[dy * IN_H + dx], wp[dy * 3 + dx], s);
        float inv = bn1[ci] * rsqrtf(bn1[768 + ci] + EPS);
        float y = s * inv + (bn1[256 + ci] - bn1[512 + ci] * inv);
        y = fminf(fmaxf(y, 0.f), 6.f);
        u16 h = bf16_rne(y);
        float hf = __builtin_bit_cast(float, (unsigned)h << 16);
        XS[ln][ci]       = h;
        XS[ln][256 + ci] = bf16_rne(y - hf);
    }
    __syncthreads();
    const int nr = tid >> 2, seg = tid & 3;   // 4 threads per output row
    u16* orow = X3 + (size_t)(blockIdx.x * 64 + nr) * 512 + seg * 128;
    #pragma unroll
    for (int j0 = 0; j0 < 128; j0 += 8) {
        u16x8 v = *(const u16x8*)&XS[nr][seg * 128 + j0];
        *(u16x8*)(orow + j0) = v;
    }
}

// ---------------------------------------------------------------------------
// W prep: fp32 (C,C) -> hi/lo bf16 buffers for both branches
// ---------------------------------------------------------------------------
__global__ __launch_bounds__(256)
void wprep(const float* __restrict__ ws, const float* __restrict__ wk,
           u16* __restrict__ WhS, u16* __restrict__ WlS,
           u16* __restrict__ WhK, u16* __restrict__ WlK) {
    int i = blockIdx.x * 256 + threadIdx.x;
    {
        float a = ws[i];
        u16 h = bf16_rne(a);
        float hf = __builtin_bit_cast(float, (unsigned)h << 16);
        WhS[i] = h; WlS[i] = bf16_rne(a - hf);
    }
    {
        float a = wk[i];
        u16 h = bf16_rne(a);
        float hf = __builtin_bit_cast(float, (unsigned)h << 16);
        WhK[i] = h; WlK[i] = bf16_rne(a - hf);
    }
}

// ---------------------------------------------------------------------------
// MFMA GEMM: out[co,n] = BN2( sum_ci W[co,ci]*X[ci,n] + bias )
// split-bf16: acc = Wh*Xh + Wl*Xh + Wh*Xl  (t<4: hi cols, double-MFMA)
// BM=256 (all co), BN=128, BK=64. 512 thr = 8 waves (4 M x 2 N), each wave
// 64x64 via 4x4 frags of 16x16x32. global_load_lds w/ pre-swizzled source,
// XOR-swizzled ds_read_b128 (st-16x32 pattern).
// ---------------------------------------------------------------------------
template<int P>
__global__ __launch_bounds__(512)
void mfma_gemm(const u16* __restrict__ X3, const u16* __restrict__ Wh,
               const u16* __restrict__ Wl, const float* __restrict__ pw_b,
               const float* __restrict__ bn2, float* __restrict__ out) {
    __shared__ u16 Xs[8192];     // 128 rows x 64 k (128B rows)
    __shared__ u16 Whs[16384];   // 256 rows x 64 k
    __shared__ u16 Wls[16384];
    const int tid  = threadIdx.x;
    const int lane = tid & 63, wave = tid >> 6;
    const int wm = wave >> 1, wn = wave & 1;
    const int n0 = blockIdx.x * 128;
    const int swz  = (lane & 7) ^ (lane >> 3);  // 16B-chunk permutation (involution)
    const int rsub = lane >> 3;

    f32x4 acc[4][4] = {};

    for (int t = 0; t < 8; ++t) {
        const int kr  = t * 64;         // X3 column (0..511)
        const int krw = (t & 3) * 64;   // W column (0..255)
        #pragma unroll
        for (int ii = 0; ii < 2; ++ii) {   // X: 16 issues
            int i = wave * 2 + ii;
            int r = i * 8 + rsub;
            GLOAD16(X3 + (size_t)(n0 + r) * 512 + kr + swz * 8, (char*)Xs + i * 1024);
        }
        #pragma unroll
        for (int ii = 0; ii < 4; ++ii) {   // Wh: 32 issues
            int i = wave * 4 + ii;
            int r = i * 8 + rsub;
            GLOAD16(Wh + (size_t)r * 256 + krw + swz * 8, (char*)Whs + i * 1024);
        }
        if (t < 4) {
            #pragma unroll
            for (int ii = 0; ii < 4; ++ii) {   // Wl: 32 issues
                int i = wave * 4 + ii;
                int r = i * 8 + rsub;
                GLOAD16(Wl + (size_t)r * 256 + krw + swz * 8, (char*)Wls + i * 1024);
            }
        }
        __syncthreads();   // drains vmcnt -> tiles ready

        #pragma unroll
        for (int ks = 0; ks < 2; ++ks) {
            const int kb = ks * 64 + (lane >> 4) * 16;  // byte offset of 16B chunk
            short8 bx[4], ax[4];
            #pragma unroll
            for (int j = 0; j < 4; ++j) {
                int row = wn * 64 + j * 16 + (lane & 15);
                bx[j] = *(const short8*)((const char*)Xs + row * 128 + (kb ^ ((row & 7) << 4)));
            }
            #pragma unroll
            for (int i = 0; i < 4; ++i) {
                int row = wm * 64 + i * 16 + (lane & 15);
                ax[i] = *(const short8*)((const char*)Whs + row * 128 + (kb ^ ((row & 7) << 4)));
            }
            #pragma unroll
            for (int i = 0; i < 4; ++i)
                #pragma unroll
                for (int j = 0; j < 4; ++j)
                    acc[i][j] = __builtin_amdgcn_mfma_f32_16x16x32_bf16(ax[i], bx[j], acc[i][j], 0, 0, 0);
            if (t < 4) {
                #pragma unroll
                for (int i = 0; i < 4; ++i) {
                    int row = wm * 64 + i * 16 + (lane & 15);
                    ax[i] = *(const short8*)((const char*)Wls + row * 128 + (kb ^ ((row & 7) << 4)));
                }
                #pragma unroll
                for (int i = 0; i < 4; ++i)
                    #pragma unroll
                    for (int j = 0; j < 4; ++j)
                        acc[i][j] = __builtin_amdgcn_mfma_f32_16x16x32_bf16(ax[i], bx[j], acc[i][j], 0, 0, 0);
            }
        }
        __syncthreads();
    }

    // epilogue: BN2 + bias, store fp32
    int bj[4], pj[4];
    #pragma unroll
    for (int j = 0; j < 4; ++j) {
        int nn = n0 + wn * 64 + j * 16 + (lane & 15);
        bj[j] = nn / P; pj[j] = nn - bj[j] * P;
    }
    #pragma unroll
    for (int i = 0; i < 4; ++i) {
        #pragma unroll
        for (int r = 0; r < 4; ++r) {
            int co = wm * 64 + i * 16 + (lane >> 4) * 4 + r;
            float inv = bn2[co] * rsqrtf(bn2[768 + co] + EPS);
            float sh  = bn2[256 + co] - bn2[512 + co] * inv + pw_b[co] * inv;
            #pragma unroll
            for (int j = 0; j < 4; ++j)
                out[((size_t)bj[j] * C + co) * P + pj[j]] = acc[i][j][r] * inv + sh;
        }
    }
}

// ---------------------------------------------------------------------------
// xcorr: out[b,c] = s[b,c](29x29) corr k[b,c](5x5) -> 25x25
// ---------------------------------------------------------------------------
__global__ __launch_bounds__(256)
void xcorr_kernel(const float* __restrict__ s, const float* __restrict__ k,
                  float* __restrict__ out) {
    const int bc = blockIdx.x;
    __shared__ float ss[841];
    __shared__ float ks[25];
    const float* sp = s + (size_t)bc * 841;
    const float* kp = k + (size_t)bc * 25;
    const int tid = threadIdx.x;
    for (int i = tid; i < 841; i += 256) ss[i] = sp[i];
    if (tid < 25) ks[tid] = kp[tid];
    __syncthreads();
    float* op = out + (size_t)bc * 625;
    for (int p = tid; p < 625; p += 256) {
        int oh = p / 25, ow = p - (p / 25) * 25;
        float acc = 0.f;
        #pragma unroll
        for (int i = 0; i < 5; i++)
            #pragma unroll
            for (int j = 0; j < 5; j++)
                acc = fmaf(ss[(oh + i) * 29 + ow + j], ks[i * 5 + j], acc);
        op[p] = acc;
    }
}

// ---------------------------------------------------------------------------
// Fallback (round-1 path) in case ws_size < 228 MB
// ---------------------------------------------------------------------------
template<int IN_H>
__global__ __launch_bounds__(256)
void branch_fallback(const float* __restrict__ in, const float* __restrict__ dw_w,
                     const float* __restrict__ bn1, const float* __restrict__ pw_w,
                     const float* __restrict__ pw_b, const float* __restrict__ bn2,
                     float* __restrict__ out) {
    constexpr int OUT_H = IN_H - 2;
    constexpr int P = OUT_H * OUT_H;
    const int n0  = blockIdx.x * 64;
    const int co0 = blockIdx.y * 64;
    const int tid = threadIdx.x;
    const int tx = tid & 15, ty = tid >> 4;
    __shared__ __align__(16) float Ws[16][64];
    __shared__ __align__(16) float Xs2[16][64];
    float acc[4][4] = {};
    for (int k0 = 0; k0 < C; k0 += 16) {
        #pragma unroll
        for (int e = 0; e < 4; e++) {
            int idx = e * 256 + tid;
            int m = idx & 63, kk = idx >> 6;
            Ws[kk][m] = pw_w[(co0 + m) * C + (k0 + kk)];
        }
        #pragma unroll
        for (int e = 0; e < 4; e++) {
            int idx = e * 256 + tid;
            int nn = idx & 63, kk = idx >> 6;
            int ci = k0 + kk;
            int n = n0 + nn;
            int b = n / P, p = n - b * P;
            int oh = p / OUT_H, ow = p - oh * OUT_H;
            const float* ip = in + (((size_t)b * C + ci) * IN_H + oh) * IN_H + ow;
            const float* wp = dw_w + ci * 9;
            float s = 0.f;
            #pragma unroll
            for (int dy = 0; dy < 3; dy++)
                #pragma unroll
                for (int dx = 0; dx < 3; dx++)
                    s = fmaf(ip[dy * IN_H + dx], wp[dy * 3 + dx], s);
            float inv = bn1[ci] * rsqrtf(bn1[3 * C + ci] + EPS);
            float y = s * inv + (bn1[C + ci] - bn1[2 * C + ci] * inv);
            Xs2[kk][nn] = fminf(fmaxf(y, 0.f), 6.f);
        }
        __syncthreads();
        #pragma unroll
        for (int kk = 0; kk < 16; kk++) {
            float4 av = *reinterpret_cast<const float4*>(&Ws[kk][ty * 4]);
            float4 bv = *reinterpret_cast<const float4*>(&Xs2[kk][tx * 4]);
            float a[4] = {av.x, av.y, av.z, av.w};
            float bb[4] = {bv.x, bv.y, bv.z, bv.w};
            #pragma unroll
            for (int i = 0; i < 4; i++)
                #pragma unroll
                for (int j = 0; j < 4; j++)
                    acc[i][j] = fmaf(a[i], bb[j], acc[i][j]);
        }
        __syncthreads();
    }
    #pragma unroll
    for (int i = 0; i < 4; i++) {
        int co = co0 + ty * 4 + i;
        float inv = bn2[co] * rsqrtf(bn2[3 * C + co] + EPS);
        float sh  = (bn2[C + co] - bn2[2 * C + co] * inv) + pw_b[co] * inv;
        int n = n0 + tx * 4;
        #pragma unroll
        for (int j = 0; j < 4; j++) {
            int nj = n + j;
            int bj2 = nj / P, pj2 = nj - bj2 * P;
            out[((size_t)bj2 * C + co) * P + pj2] = acc[i][j] * inv + sh;
        }
    }
}

extern "C" void kernel_launch(void* const* d_in, const int* in_sizes, int n_in,
                              void* d_out, int out_size, void* d_ws, size_t ws_size,
                              hipStream_t stream) {
    const float* kernel = (const float*)d_in[0];
    const float* search = (const float*)d_in[1];
    const float* k_dw_w = (const float*)d_in[2];
    const float* k_bn1  = (const float*)d_in[3];
    const float* k_pw_w = (const float*)d_in[4];
    const float* k_pw_b = (const float*)d_in[5];
    const float* k_bn2  = (const float*)d_in[6];
    const float* s_dw_w = (const float*)d_in[7];
    const float* s_bn1  = (const float*)d_in[8];
    const float* s_pw_w = (const float*)d_in[9];
    const float* s_pw_b = (const float*)d_in[10];
    const float* s_bn2  = (const float*)d_in[11];

    constexpr size_t NS = (size_t)B * 841;            // 107648 search cols
    constexpr size_t NK = (size_t)B * 25;             // 3200 kernel cols
    constexpr size_t X3S_B = NS * 512 * 2;            // 110,231,552
    constexpr size_t X3K_B = NK * 512 * 2;            //   3,276,800
    constexpr size_t S_B   = NS * C * 4 / B * B;      // 110,231,552 (B*C*841*4)
    constexpr size_t K_B   = NK * C * 4 / B * B;      //   3,276,800
    constexpr size_t W_B   = (size_t)C * C * 2;       //     131,072
    constexpr size_t NEED  = X3S_B + X3K_B + (size_t)B * C * 841 * 4 +
                             (size_t)B * C * 25 * 4 + 4 * W_B;

    if (ws_size >= NEED) {
        char* base = (char*)d_ws;
        u16*   X3s = (u16*)base;                 base += X3S_B;
        u16*   X3k = (u16*)base;                 base += X3K_B;
        float* Sb  = (float*)base;               base += (size_t)B * C * 841 * 4;
        float* Kb  = (float*)base;               base += (size_t)B * C * 25 * 4;
        u16* WhS = (u16*)base;                   base += W_B;
        u16* WlS = (u16*)base;                   base += W_B;
        u16* WhK = (u16*)base;                   base += W_B;
        u16* WlK = (u16*)base;

        wprep<<<dim3(256), dim3(256), 0, stream>>>(s_pw_w, k_pw_w, WhS, WlS, WhK, WlK);
        dw_pass<31><<<dim3(NS / 64), dim3(256), 0, stream>>>(search, s_dw_w, s_bn1, X3s);
        dw_pass<7><<<dim3(NK / 64), dim3(256), 0, stream>>>(kernel, k_dw_w, k_bn1, X3k);
        mfma_gemm<841><<<dim3(NS / 128), dim3(512), 0, stream>>>(X3s, WhS, WlS, s_pw_b, s_bn2, Sb);
        mfma_gemm<25><<<dim3(NK / 128), dim3(512), 0, stream>>>(X3k, WhK, WlK, k_pw_b, k_bn2, Kb);
        xcorr_kernel<<<dim3(B * C), dim3(256), 0, stream>>>(Sb, Kb, (float*)d_out);
    } else {
        float* s_buf = (float*)d_ws;
        float* k_buf = s_buf + (size_t)B * C * 29 * 29;
        branch_fallback<7><<<dim3(50, 4), dim3(256), 0, stream>>>(
            kernel, k_dw_w, k_bn1, k_pw_w, k_pw_b, k_bn2, k_buf);
        branch_fallback<31><<<dim3(1682, 4), dim3(256), 0, stream>>>(
            search, s_dw_w, s_bn1, s_pw_w, s_pw_b, s_bn2, s_buf);
        xcorr_kernel<<<dim3(B * C), dim3(256), 0, stream>>>(s_buf, k_buf, (float*)d_out);
    }
}

// Round 4
// 298.084 us; speedup vs baseline: 2.3153x; 1.2355x over previous
//
#include <hip/hip_runtime.h>

constexpr int B = 128, C = 256;
constexpr float EPS = 1e-5f;

typedef unsigned short u16;
typedef short short8 __attribute__((ext_vector_type(8)));
typedef u16 u16x8 __attribute__((ext_vector_type(8)));
typedef float f32x4 __attribute__((ext_vector_type(4)));

__device__ __forceinline__ u16 bf16_rne(float x) {
    unsigned u = __builtin_bit_cast(unsigned, x);
    return (u16)((u + 0x7FFFu + ((u >> 16) & 1u)) >> 16);
}

#define GLOAD16(g, l)                                                              \
    __builtin_amdgcn_global_load_lds(                                              \
        (const __attribute__((address_space(1))) unsigned int*)(g),                \
        (__attribute__((address_space(3))) unsigned int*)(l), 16, 0, 0)

// ---------------------------------------------------------------------------
// W prep: fp32 (C,C) -> interleaved hi/lo bf16: Wc[co][kb][ {hi:32 | lo:32} ]
// (co: 256, kb: 8 blocks of 32 k) -> row stride 512 u16 per co.
// ---------------------------------------------------------------------------
__global__ __launch_bounds__(256)
void wprep(const float* __restrict__ ws, const float* __restrict__ wk,
           u16* __restrict__ WcS, u16* __restrict__ WcK) {
    int i = blockIdx.x * 256 + threadIdx.x;     // i over 65536 = co*256 + k
    int co = i >> 8, k = i & 255;
    size_t o = (size_t)co * 512 + (k >> 5) * 64 + (k & 31);
    {
        float a = ws[i];
        u16 h = bf16_rne(a);
        float hf = __builtin_bit_cast(float, (unsigned)h << 16);
        WcS[o] = h; WcS[o + 32] = bf16_rne(a - hf);
    }
    {
        float a = wk[i];
        u16 h = bf16_rne(a);
        float hf = __builtin_bit_cast(float, (unsigned)h << 16);
        WcK[o] = h; WcK[o + 32] = bf16_rne(a - hf);
    }
}

// ---------------------------------------------------------------------------
// Fused: dwconv3x3+BN1+ReLU6 (in-register -> swizzled LDS X tile)
//        -> split-bf16 MFMA GEMM (Wh*Xh + Wl*Xh + Wh*Xl) -> bias+BN2.
// BM=256 (all co; dwconv done exactly once), BN=128, BK=32.
// LDS rows are 128 B = [32 u16 hi | 32 u16 lo], 8 chunks of 16 B;
// XOR swizzle byte ^= ((row&7)<<4) is closed within the row (bug-fix vs r3).
// W staged via pre-swizzled global_load_lds from interleaved Wc; X written
// via swizzled ds_write_b128. 512 thr, 8 waves (4M x 2N), wave tile 64x64.
// ---------------------------------------------------------------------------
template<int IN_H>
__global__ __launch_bounds__(512)
void fused_branch(const float* __restrict__ in, const float* __restrict__ dw_w,
                  const float* __restrict__ bn1, const u16* __restrict__ Wc,
                  const float* __restrict__ pw_b, const float* __restrict__ bn2,
                  float* __restrict__ out) {
    constexpr int OUT_H = IN_H - 2, P = OUT_H * OUT_H, IHW = IN_H * IN_H;
    __shared__ u16 XS[128 * 64];   // 128 n-rows x (32 hi | 32 lo), swizzled
    __shared__ u16 WS[256 * 64];   // 256 co-rows x (32 hi | 32 lo), swizzled

    const int tid = threadIdx.x;
    const int lane = tid & 63, wave = tid >> 6;
    const int wm = wave >> 1, wn = wave & 1;
    const int n0 = blockIdx.x * 128;

    // dwconv assignment: n_local = tid&127, ci-octet = tid>>7 (0..3)
    const int nl = tid & 127;
    const int oct = tid >> 7;
    const int n = n0 + nl;
    const int b = n / P, p = n - b * P;
    const int oh = p / OUT_H, ow = p - oh * OUT_H;
    const float* ip0 = in + ((size_t)b * C * IN_H + oh) * IN_H + ow;
    const int xhi_byte = nl * 128 + ((oct * 16) ^ ((nl & 7) << 4));  // lo = ^64

    f32x4 acc[4][4] = {};

    #pragma unroll 1
    for (int t = 0; t < 8; ++t) {
        const int k0 = t * 32;
        // ---- stage W tile: 2048 chunks, 4 per thread, pre-swizzled source
        #pragma unroll
        for (int ii = 0; ii < 4; ++ii) {
            int c = (wave * 4 + ii) * 64 + lane;          // chunk index [0,2048)
            int row = c >> 3, k16 = c & 7;
            int sb = (k16 * 16) ^ ((row & 7) << 4);       // swizzled byte in 128B row
            GLOAD16(Wc + (size_t)row * 512 + t * 64 + (sb >> 1), (char*)WS + c * 16);
        }
        // ---- dwconv+BN1+ReLU6 for 8 ci, split hi/lo, swizzled ds_write_b128
        {
            const int ci0 = k0 + oct * 8;
            u16x8 hx, lx;
            #pragma unroll
            for (int q = 0; q < 8; ++q) {
                int ci = ci0 + q;
                const float* ip = ip0 + (size_t)ci * IHW;
                const float* wp = dw_w + ci * 9;
                float s = 0.f;
                #pragma unroll
                for (int dy = 0; dy < 3; dy++)
                    #pragma unroll
                    for (int dx = 0; dx < 3; dx++)
                        s = fmaf(ip[dy * IN_H + dx], wp[dy * 3 + dx], s);
                float inv = bn1[ci] * rsqrtf(bn1[3 * C + ci] + EPS);
                float y = s * inv + (bn1[C + ci] - bn1[2 * C + ci] * inv);
                y = fminf(fmaxf(y, 0.f), 6.f);
                u16 h = bf16_rne(y);
                float hf = __builtin_bit_cast(float, (unsigned)h << 16);
                hx[q] = h;
                lx[q] = bf16_rne(y - hf);
            }
            *(u16x8*)((char*)XS + xhi_byte)        = hx;
            *(u16x8*)((char*)XS + (xhi_byte ^ 64)) = lx;
        }
        __syncthreads();   // drains vmcnt + lgkm: tiles ready

        // ---- MFMA: 3 products
        const int kb = (lane >> 4) * 16;   // hi chunk byte; lo = ^64
        short8 bxh[4], bxl[4], aw[4];
        #pragma unroll
        for (int j = 0; j < 4; ++j) {
            int row = wn * 64 + j * 16 + (lane & 15);
            int off = row * 128 + (kb ^ ((row & 7) << 4));
            bxh[j] = *(const short8*)((const char*)XS + off);
            bxl[j] = *(const short8*)((const char*)XS + (off ^ 64));
        }
        #pragma unroll
        for (int i = 0; i < 4; ++i) {
            int row = wm * 64 + i * 16 + (lane & 15);
            aw[i] = *(const short8*)((const char*)WS + (row * 128 + (kb ^ ((row & 7) << 4))));
        }
        #pragma unroll
        for (int i = 0; i < 4; ++i)
            #pragma unroll
            for (int j = 0; j < 4; ++j) {
                acc[i][j] = __builtin_amdgcn_mfma_f32_16x16x32_bf16(aw[i], bxh[j], acc[i][j], 0, 0, 0);
                acc[i][j] = __builtin_amdgcn_mfma_f32_16x16x32_bf16(aw[i], bxl[j], acc[i][j], 0, 0, 0);
            }
        #pragma unroll
        for (int i = 0; i < 4; ++i) {
            int row = wm * 64 + i * 16 + (lane & 15);
            aw[i] = *(const short8*)((const char*)WS + ((row * 128 + (kb ^ ((row & 7) << 4))) ^ 64));
        }
        #pragma unroll
        for (int i = 0; i < 4; ++i)
            #pragma unroll
            for (int j = 0; j < 4; ++j)
                acc[i][j] = __builtin_amdgcn_mfma_f32_16x16x32_bf16(aw[i], bxh[j], acc[i][j], 0, 0, 0);
        __syncthreads();
    }

    // ---- epilogue: bias + BN2, fp32 store (layout validated in r1/r2)
    int bj[4], pj[4];
    #pragma unroll
    for (int j = 0; j < 4; ++j) {
        int nn = n0 + wn * 64 + j * 16 + (lane & 15);
        bj[j] = nn / P; pj[j] = nn - bj[j] * P;
    }
    #pragma unroll
    for (int i = 0; i < 4; ++i) {
        #pragma unroll
        for (int r = 0; r < 4; ++r) {
            int co = wm * 64 + i * 16 + (lane >> 4) * 4 + r;
            float inv = bn2[co] * rsqrtf(bn2[3 * C + co] + EPS);
            float sh  = bn2[C + co] - bn2[2 * C + co] * inv + pw_b[co] * inv;
            #pragma unroll
            for (int j = 0; j < 4; ++j)
                out[((size_t)bj[j] * C + co) * P + pj[j]] = acc[i][j][r] * inv + sh;
        }
    }
}

// ---------------------------------------------------------------------------
// xcorr v2: 10 (b,c) pairs per 256-thr block; 25 threads per pair, each
// computes a 5x5 output tile (81 LDS reads / 625 FMA per 25 outputs).
// ---------------------------------------------------------------------------
__global__ __launch_bounds__(256)
void xcorr2(const float* __restrict__ s, const float* __restrict__ k,
            float* __restrict__ out) {
    const int bc0 = blockIdx.x * 10;
    const int nbc = min(10, B * C - bc0);
    __shared__ float ss[10 * 841];
    __shared__ float ks[10 * 25];
    const int tid = threadIdx.x;
    for (int i = tid; i < nbc * 841; i += 256) ss[i] = s[(size_t)bc0 * 841 + i];
    for (int i = tid; i < nbc * 25; i += 256) ks[i] = k[(size_t)bc0 * 25 + i];
    __syncthreads();

    const int lb = tid / 25, lt = tid - lb * 25;
    if (lb >= nbc) return;
    const int ohg = lt / 5, owg = lt - ohg * 5;
    const float* sp = ss + lb * 841 + (ohg * 5) * 29 + owg * 5;
    float kk[25];
    #pragma unroll
    for (int q = 0; q < 25; ++q) kk[q] = ks[lb * 25 + q];

    float acc[5][5] = {};
    #pragma unroll
    for (int ir = 0; ir < 9; ++ir) {
        float row[9];
        #pragma unroll
        for (int j = 0; j < 9; ++j) row[j] = sp[ir * 29 + j];
        #pragma unroll
        for (int oi = 0; oi < 5; ++oi) {
            int ki = ir - oi;
            if (ki < 0 || ki > 4) continue;
            #pragma unroll
            for (int oj = 0; oj < 5; ++oj)
                #pragma unroll
                for (int kj = 0; kj < 5; ++kj)
                    acc[oi][oj] = fmaf(row[oj + kj], kk[ki * 5 + kj], acc[oi][oj]);
        }
    }
    float* op = out + (size_t)(bc0 + lb) * 625;
    #pragma unroll
    for (int oi = 0; oi < 5; ++oi)
        #pragma unroll
        for (int oj = 0; oj < 5; ++oj)
            op[(ohg * 5 + oi) * 25 + owg * 5 + oj] = acc[oi][oj];
}

// ---------------------------------------------------------------------------
// Fallback (round-1 fp32 path) in case ws_size is too small
// ---------------------------------------------------------------------------
template<int IN_H>
__global__ __launch_bounds__(256)
void branch_fallback(const float* __restrict__ in, const float* __restrict__ dw_w,
                     const float* __restrict__ bn1, const float* __restrict__ pw_w,
                     const float* __restrict__ pw_b, const float* __restrict__ bn2,
                     float* __restrict__ out) {
    constexpr int OUT_H = IN_H - 2;
    constexpr int P = OUT_H * OUT_H;
    const int n0  = blockIdx.x * 64;
    const int co0 = blockIdx.y * 64;
    const int tid = threadIdx.x;
    const int tx = tid & 15, ty = tid >> 4;
    __shared__ __align__(16) float Ws[16][64];
    __shared__ __align__(16) float Xs2[16][64];
    float acc[4][4] = {};
    for (int k0 = 0; k0 < C; k0 += 16) {
        #pragma unroll
        for (int e = 0; e < 4; e++) {
            int idx = e * 256 + tid;
            int m = idx & 63, kk = idx >> 6;
            Ws[kk][m] = pw_w[(co0 + m) * C + (k0 + kk)];
        }
        #pragma unroll
        for (int e = 0; e < 4; e++) {
            int idx = e * 256 + tid;
            int nn = idx & 63, kk = idx >> 6;
            int ci = k0 + kk;
            int n = n0 + nn;
            int b = n / P, p = n - b * P;
            int oh = p / OUT_H, ow = p - oh * OUT_H;
            const float* ip = in + (((size_t)b * C + ci) * IN_H + oh) * IN_H + ow;
            const float* wp = dw_w + ci * 9;
            float s = 0.f;
            #pragma unroll
            for (int dy = 0; dy < 3; dy++)
                #pragma unroll
                for (int dx = 0; dx < 3; dx++)
                    s = fmaf(ip[dy * IN_H + dx], wp[dy * 3 + dx], s);
            float inv = bn1[ci] * rsqrtf(bn1[3 * C + ci] + EPS);
            float y = s * inv + (bn1[C + ci] - bn1[2 * C + ci] * inv);
            Xs2[kk][nn] = fminf(fmaxf(y, 0.f), 6.f);
        }
        __syncthreads();
        #pragma unroll
        for (int kk = 0; kk < 16; kk++) {
            float4 av = *reinterpret_cast<const float4*>(&Ws[kk][ty * 4]);
            float4 bv = *reinterpret_cast<const float4*>(&Xs2[kk][tx * 4]);
            float a[4] = {av.x, av.y, av.z, av.w};
            float bb[4] = {bv.x, bv.y, bv.z, bv.w};
            #pragma unroll
            for (int i = 0; i < 4; i++)
                #pragma unroll
                for (int j = 0; j < 4; j++)
                    acc[i][j] = fmaf(a[i], bb[j], acc[i][j]);
        }
        __syncthreads();
    }
    #pragma unroll
    for (int i = 0; i < 4; i++) {
        int co = co0 + ty * 4 + i;
        float inv = bn2[co] * rsqrtf(bn2[3 * C + co] + EPS);
        float sh  = (bn2[C + co] - bn2[2 * C + co] * inv) + pw_b[co] * inv;
        int n = n0 + tx * 4;
        #pragma unroll
        for (int j = 0; j < 4; j++) {
            int nj = n + j;
            int bj2 = nj / P, pj2 = nj - bj2 * P;
            out[((size_t)bj2 * C + co) * P + pj2] = acc[i][j] * inv + sh;
        }
    }
}

extern "C" void kernel_launch(void* const* d_in, const int* in_sizes, int n_in,
                              void* d_out, int out_size, void* d_ws, size_t ws_size,
                              hipStream_t stream) {
    const float* kernel = (const float*)d_in[0];
    const float* search = (const float*)d_in[1];
    const float* k_dw_w = (const float*)d_in[2];
    const float* k_bn1  = (const float*)d_in[3];
    const float* k_pw_w = (const float*)d_in[4];
    const float* k_pw_b = (const float*)d_in[5];
    const float* k_bn2  = (const float*)d_in[6];
    const float* s_dw_w = (const float*)d_in[7];
    const float* s_bn1  = (const float*)d_in[8];
    const float* s_pw_w = (const float*)d_in[9];
    const float* s_pw_b = (const float*)d_in[10];
    const float* s_bn2  = (const float*)d_in[11];

    constexpr size_t NS = (size_t)B * 841;            // 107648 search cols
    constexpr size_t NK = (size_t)B * 25;             // 3200 kernel cols
    constexpr size_t SB_B = (size_t)B * C * 841 * 4;  // 110,231,552
    constexpr size_t KB_B = (size_t)B * C * 25 * 4;   //   3,276,800
    constexpr size_t W_B  = (size_t)C * 512 * 2;      //     262,144 (interleaved)
    constexpr size_t NEED = SB_B + KB_B + 2 * W_B;

    if (ws_size >= NEED) {
        char* base = (char*)d_ws;
        float* Sb = (float*)base;   base += SB_B;
        float* Kb = (float*)base;   base += KB_B;
        u16* WcS = (u16*)base;      base += W_B;
        u16* WcK = (u16*)base;

        wprep<<<dim3(256), dim3(256), 0, stream>>>(s_pw_w, k_pw_w, WcS, WcK);
        fused_branch<31><<<dim3(NS / 128), dim3(512), 0, stream>>>(
            search, s_dw_w, s_bn1, WcS, s_pw_b, s_bn2, Sb);
        fused_branch<7><<<dim3(NK / 128), dim3(512), 0, stream>>>(
            kernel, k_dw_w, k_bn1, WcK, k_pw_b, k_bn2, Kb);
        xcorr2<<<dim3((B * C + 9) / 10), dim3(256), 0, stream>>>(Sb, Kb, (float*)d_out);
    } else {
        float* s_buf = (float*)d_ws;
        float* k_buf = s_buf + (size_t)B * C * 29 * 29;
        branch_fallback<7><<<dim3(50, 4), dim3(256), 0, stream>>>(
            kernel, k_dw_w, k_bn1, k_pw_w, k_pw_b, k_bn2, k_buf);
        branch_fallback<31><<<dim3(1682, 4), dim3(256), 0, stream>>>(
            search, s_dw_w, s_bn1, s_pw_w, s_pw_b, s_bn2, s_buf);
        xcorr2<<<dim3((B * C + 9) / 10), dim3(256), 0, stream>>>(s_buf, k_buf, (float*)d_out);
    }
}

// Round 5
// 220.343 us; speedup vs baseline: 3.1322x; 1.3528x over previous
//
#include <hip/hip_runtime.h>

constexpr int B = 128, C = 256;
constexpr float EPS = 1e-5f;
constexpr int NSG = B * 841;   // 107648 search GEMM columns
constexpr int NKG = B * 25;    // 3200 kernel GEMM columns

typedef unsigned short u16;
typedef short short8 __attribute__((ext_vector_type(8)));
typedef u16 u16x8 __attribute__((ext_vector_type(8)));
typedef float f32x4 __attribute__((ext_vector_type(4)));

__device__ __forceinline__ u16 bf16_rne(float x) {
    unsigned u = __builtin_bit_cast(unsigned, x);
    return (u16)((u + 0x7FFFu + ((u >> 16) & 1u)) >> 16);
}

#define GLOAD16(g, l)                                                              \
    __builtin_amdgcn_global_load_lds(                                              \
        (const __attribute__((address_space(1))) unsigned int*)(g),                \
        (__attribute__((address_space(3))) unsigned int*)(l), 16, 0, 0)

// ---------------------------------------------------------------------------
// W prep: fp32 (C,C) -> interleaved hi/lo bf16: Wc[co][kb][ {hi:32 | lo:32} ]
// ---------------------------------------------------------------------------
__global__ __launch_bounds__(256)
void wprep(const float* __restrict__ ws, const float* __restrict__ wk,
           u16* __restrict__ WcS, u16* __restrict__ WcK) {
    int i = blockIdx.x * 256 + threadIdx.x;     // co*256 + k
    int co = i >> 8, k = i & 255;
    size_t o = (size_t)co * 512 + (k >> 5) * 64 + (k & 31);
    {
        float a = ws[i];
        u16 h = bf16_rne(a);
        float hf = __builtin_bit_cast(float, (unsigned)h << 16);
        WcS[o] = h; WcS[o + 32] = bf16_rne(a - hf);
    }
    {
        float a = wk[i];
        u16 h = bf16_rne(a);
        float hf = __builtin_bit_cast(float, (unsigned)h << 16);
        WcK[o] = h; WcK[o + 32] = bf16_rne(a - hf);
    }
}

// ---------------------------------------------------------------------------
// dw_pass2: depthwise 3x3 + BN1 + ReLU6 -> X3h/X3l planes [kc][n][8 u16].
// Block = (b, group of CG channels). Input staged to LDS (XOR-swizzled padded
// rows), register-sliding 8-wide strips, LDS-transpose, coalesced 16B writes.
// ---------------------------------------------------------------------------
template<int IN_H, int CG>
__global__ __launch_bounds__(256)
void dw_pass2(const float* __restrict__ in, const float* __restrict__ dw_w,
              const float* __restrict__ bn1,
              u16* __restrict__ X3h, u16* __restrict__ X3l) {
    constexpr int OUT_H = IN_H - 2, ON = OUT_H * OUT_H, IHW = IN_H * IN_H;
    constexpr int PADW  = (IN_H + 7) & ~7;        // 32 or 8
    constexpr int ROWCH = PADW / 4;               // 16B chunks per row (8 or 2)
    constexpr int NSTRIP = (OUT_H + 7) / 8;       // 4 or 1
    constexpr int NF4 = CG * IHW / 4;             // exact (1922 / 392)
    constexpr int SUBS = CG / 8;
    constexpr int NSP = B * ON;
    constexpr unsigned SM_IN = CG * IN_H * PADW * 4;
    constexpr unsigned SM_XT = 2u * ON * CG * 2;
    constexpr unsigned SMSZ = SM_IN > SM_XT ? SM_IN : SM_XT;
    __shared__ __align__(16) char SMEM[SMSZ];
    u16* xt = (u16*)SMEM;   // reused after compute: [2][ON][CG]

    const int tid = threadIdx.x;
    const int b = blockIdx.x, g = blockIdx.y;
    const int ci0 = g * CG;
    const float* src = in + ((size_t)b * C + ci0) * IHW;

    // ---- stage input: coalesced float4 reads, swizzled scatter to padded LDS
    #pragma unroll
    for (int r = 0; r < (NF4 + 255) / 256; ++r) {
        int q = r * 256 + tid;
        if (q < NF4) {
            float4 v = ((const float4*)src)[q];
            float vv[4] = {v.x, v.y, v.z, v.w};
            #pragma unroll
            for (int e = 0; e < 4; ++e) {
                int idx = q * 4 + e;
                int cl = idx / IHW, rem = idx - cl * IHW;
                int ih = rem / IN_H, iw = rem - ih * IN_H;
                int rowb = (cl * IN_H + ih) * PADW * 4;
                int byt = rowb + ((((iw >> 2) ^ (ih & (ROWCH - 1))) << 4) | ((iw & 3) << 2));
                *(float*)(SMEM + byt) = vv[e];
            }
        }
    }
    __syncthreads();

    // ---- compute: task = (channel cl, output row oh)
    const bool active = tid < CG * OUT_H;
    int cl = 0, oh = 0;
    if (active) { cl = tid / OUT_H; oh = tid - cl * OUT_H; }
    unsigned outv[NSTRIP][8];
    if (active) {
        const int ci = ci0 + cl;
        float wreg[9];
        #pragma unroll
        for (int q = 0; q < 9; ++q) wreg[q] = dw_w[ci * 9 + q];
        const float inv = bn1[ci] * rsqrtf(bn1[3 * C + ci] + EPS);
        const float shv = bn1[C + ci] - bn1[2 * C + ci] * inv;
        #pragma unroll
        for (int s = 0; s < NSTRIP; ++s) {
            float res[8] = {0.f, 0.f, 0.f, 0.f, 0.f, 0.f, 0.f, 0.f};
            #pragma unroll
            for (int dy = 0; dy < 3; ++dy) {
                const int ih = oh + dy;
                const char* rowb = SMEM + (cl * IN_H + ih) * PADW * 4;
                const int msk = ih & (ROWCH - 1);
                float4 A = *(const float4*)(rowb + (((2 * s + 0) ^ msk) << 4));
                float4 Bv = *(const float4*)(rowb + (((2 * s + 1) ^ msk) << 4));
                float4 Cv = (8 * s + 8 < PADW)
                              ? *(const float4*)(rowb + (((2 * s + 2) ^ msk) << 4)) : Bv;
                float x[12] = {A.x, A.y, A.z, A.w, Bv.x, Bv.y, Bv.z, Bv.w,
                               Cv.x, Cv.y, Cv.z, Cv.w};
                #pragma unroll
                for (int o = 0; o < 8; ++o)
                    res[o] = fmaf(x[o], wreg[dy * 3],
                              fmaf(x[o + 1], wreg[dy * 3 + 1],
                               fmaf(x[o + 2], wreg[dy * 3 + 2], res[o])));
            }
            #pragma unroll
            for (int o = 0; o < 8; ++o) {
                float y = res[o] * inv + shv;
                y = fminf(fmaxf(y, 0.f), 6.f);
                u16 h = bf16_rne(y);
                float hf = __builtin_bit_cast(float, (unsigned)h << 16);
                outv[s][o] = (unsigned)h | ((unsigned)bf16_rne(y - hf) << 16);
            }
        }
    }
    __syncthreads();   // input LDS now free

    // ---- transpose: scatter into xt[plane][n][cl]
    if (active) {
        #pragma unroll
        for (int s = 0; s < NSTRIP; ++s) {
            const int ow0 = s * 8;
            #pragma unroll
            for (int o = 0; o < 8; ++o) {
                if (ow0 + o < OUT_H) {
                    int n = oh * OUT_H + ow0 + o;
                    xt[(size_t)n * CG + cl]            = (u16)outv[s][o];
                    xt[((size_t)ON + n) * CG + cl]     = (u16)(outv[s][o] >> 16);
                }
            }
        }
    }
    __syncthreads();

    // ---- coalesced 16B writes to the planes
    constexpr int NCH = 2 * ON * SUBS;
    for (int q = tid; q < NCH; q += 256) {
        int plane = q / (ON * SUBS);
        int r2 = q - plane * (ON * SUBS);
        int sub = r2 / ON, n = r2 - sub * ON;
        u16x8 v = *(const u16x8*)&xt[((size_t)plane * ON + n) * CG + sub * 8];
        u16* dst = (plane ? X3l : X3h) +
                   ((size_t)(g * SUBS + sub) * NSP + (size_t)b * ON + n) * 8;
        *(u16x8*)dst = v;
    }
}

// ---------------------------------------------------------------------------
// gemm2: out[co,n] = BN2( sum_ci W[co,ci]*X[ci,n] + bias ), split-bf16 MFMA.
// BM=256, BN=128, BK=32; double-buffered LDS, counted vmcnt(6) pipeline.
// ---------------------------------------------------------------------------
template<int PQ>
__global__ __launch_bounds__(512)
void gemm2(const u16* __restrict__ X3h, const u16* __restrict__ X3l,
           const u16* __restrict__ Wc, const float* __restrict__ pw_b,
           const float* __restrict__ bn2, float* __restrict__ out) {
    constexpr int NSP = B * PQ;
    __shared__ u16 XS[2][128 * 64];   // 16KB each: 128 n-rows x [32 hi|32 lo]
    __shared__ u16 WS[2][256 * 64];   // 32KB each: 256 co-rows x [32 hi|32 lo]

    const int tid = threadIdx.x;
    const int lane = tid & 63, wave = tid >> 6;
    const int wm = wave >> 1, wn = wave & 1;
    const int n0 = blockIdx.x * 128;

    auto stage = [&](int d, int t) {
        #pragma unroll
        for (int ii = 0; ii < 4; ++ii) {           // W: 2048 chunks
            int c = (wave * 4 + ii) * 64 + lane;
            int row = c >> 3, k16 = c & 7;
            int sb = (k16 * 16) ^ ((row & 7) << 4);
            GLOAD16(Wc + (size_t)row * 512 + t * 64 + (sb >> 1), (char*)WS[d] + c * 16);
        }
        #pragma unroll
        for (int ii = 0; ii < 2; ++ii) {           // X: 1024 chunks
            int c = (wave * 2 + ii) * 64 + lane;
            int row = c >> 3, m = c & 7;
            int u = m ^ (row & 7);                 // unswizzled chunk
            const u16* pl = (u < 4) ? X3h : X3l;
            int kc = t * 4 + (u & 3);
            GLOAD16(pl + ((size_t)kc * NSP + n0 + row) * 8, (char*)XS[d] + c * 16);
        }
    };

    f32x4 acc[4][4] = {};
    stage(0, 0);

    for (int t = 0; t < 8; ++t) {
        const int d = t & 1;
        if (t < 7) {
            stage(d ^ 1, t + 1);
            asm volatile("s_waitcnt vmcnt(6)" ::: "memory");   // buf d complete, next stays in flight
        } else {
            asm volatile("s_waitcnt vmcnt(0)" ::: "memory");
        }
        __builtin_amdgcn_s_barrier();
        __builtin_amdgcn_sched_barrier(0);

        const u16* xs = XS[d];
        const u16* wsp = WS[d];
        const int kb = (lane >> 4) * 16;
        short8 bxh[4], bxl[4], aw[4];
        #pragma unroll
        for (int j = 0; j < 4; ++j) {
            int row = wn * 64 + j * 16 + (lane & 15);
            int off = row * 128 + (kb ^ ((row & 7) << 4));
            bxh[j] = *(const short8*)((const char*)xs + off);
            bxl[j] = *(const short8*)((const char*)xs + (off ^ 64));
        }
        #pragma unroll
        for (int i = 0; i < 4; ++i) {
            int row = wm * 64 + i * 16 + (lane & 15);
            aw[i] = *(const short8*)((const char*)wsp + (row * 128 + (kb ^ ((row & 7) << 4))));
        }
        #pragma unroll
        for (int i = 0; i < 4; ++i)
            #pragma unroll
            for (int j = 0; j < 4; ++j) {
                acc[i][j] = __builtin_amdgcn_mfma_f32_16x16x32_bf16(aw[i], bxh[j], acc[i][j], 0, 0, 0);
                acc[i][j] = __builtin_amdgcn_mfma_f32_16x16x32_bf16(aw[i], bxl[j], acc[i][j], 0, 0, 0);
            }
        #pragma unroll
        for (int i = 0; i < 4; ++i) {
            int row = wm * 64 + i * 16 + (lane & 15);
            aw[i] = *(const short8*)((const char*)wsp + ((row * 128 + (kb ^ ((row & 7) << 4))) ^ 64));
        }
        #pragma unroll
        for (int i = 0; i < 4; ++i)
            #pragma unroll
            for (int j = 0; j < 4; ++j)
                acc[i][j] = __builtin_amdgcn_mfma_f32_16x16x32_bf16(aw[i], bxh[j], acc[i][j], 0, 0, 0);

        asm volatile("s_waitcnt lgkmcnt(0)" ::: "memory");
        __builtin_amdgcn_sched_barrier(0);
        __builtin_amdgcn_s_barrier();   // raw barrier: vmem prefetch stays in flight
    }

    // ---- epilogue: bias + BN2, fp32 store (layout validated r2/r4)
    int bj[4], pj[4];
    #pragma unroll
    for (int j = 0; j < 4; ++j) {
        int nn = n0 + wn * 64 + j * 16 + (lane & 15);
        bj[j] = nn / PQ; pj[j] = nn - bj[j] * PQ;
    }
    #pragma unroll
    for (int i = 0; i < 4; ++i) {
        #pragma unroll
        for (int r = 0; r < 4; ++r) {
            int co = wm * 64 + i * 16 + (lane >> 4) * 4 + r;
            float inv = bn2[co] * rsqrtf(bn2[3 * C + co] + EPS);
            float sh  = bn2[C + co] - bn2[2 * C + co] * inv + pw_b[co] * inv;
            #pragma unroll
            for (int j = 0; j < 4; ++j)
                out[((size_t)bj[j] * C + co) * PQ + pj[j]] = acc[i][j][r] * inv + sh;
        }
    }
}

// ---------------------------------------------------------------------------
// xcorr: 10 (b,c) pairs per block; 25 threads/pair, 5x5 output tile each
// ---------------------------------------------------------------------------
__global__ __launch_bounds__(256)
void xcorr2(const float* __restrict__ s, const float* __restrict__ k,
            float* __restrict__ out) {
    const int bc0 = blockIdx.x * 10;
    const int nbc = min(10, B * C - bc0);
    __shared__ float ss[10 * 841];
    __shared__ float ks[10 * 25];
    const int tid = threadIdx.x;
    for (int i = tid; i < nbc * 841; i += 256) ss[i] = s[(size_t)bc0 * 841 + i];
    for (int i = tid; i < nbc * 25; i += 256) ks[i] = k[(size_t)bc0 * 25 + i];
    __syncthreads();

    const int lb = tid / 25, lt = tid - lb * 25;
    if (lb >= nbc) return;
    const int ohg = lt / 5, owg = lt - ohg * 5;
    const float* sp = ss + lb * 841 + (ohg * 5) * 29 + owg * 5;
    float kk[25];
    #pragma unroll
    for (int q = 0; q < 25; ++q) kk[q] = ks[lb * 25 + q];

    float acc[5][5] = {};
    #pragma unroll
    for (int ir = 0; ir < 9; ++ir) {
        float row[9];
        #pragma unroll
        for (int j = 0; j < 9; ++j) row[j] = sp[ir * 29 + j];
        #pragma unroll
        for (int oi = 0; oi < 5; ++oi) {
            int ki = ir - oi;
            if (ki < 0 || ki > 4) continue;
            #pragma unroll
            for (int oj = 0; oj < 5; ++oj)
                #pragma unroll
                for (int kj = 0; kj < 5; ++kj)
                    acc[oi][oj] = fmaf(row[oj + kj], kk[ki * 5 + kj], acc[oi][oj]);
        }
    }
    float* op = out + (size_t)(bc0 + lb) * 625;
    #pragma unroll
    for (int oi = 0; oi < 5; ++oi)
        #pragma unroll
        for (int oj = 0; oj < 5; ++oj)
            op[(ohg * 5 + oi) * 25 + owg * 5 + oj] = acc[oi][oj];
}

// ---------------------------------------------------------------------------
// Fallback (round-1 fp32 path) in case ws_size is too small
// ---------------------------------------------------------------------------
template<int IN_H>
__global__ __launch_bounds__(256)
void branch_fallback(const float* __restrict__ in, const float* __restrict__ dw_w,
                     const float* __restrict__ bn1, const float* __restrict__ pw_w,
                     const float* __restrict__ pw_b, const float* __restrict__ bn2,
                     float* __restrict__ out) {
    constexpr int OUT_H = IN_H - 2;
    constexpr int P = OUT_H * OUT_H;
    const int n0  = blockIdx.x * 64;
    const int co0 = blockIdx.y * 64;
    const int tid = threadIdx.x;
    const int tx = tid & 15, ty = tid >> 4;
    __shared__ __align__(16) float Ws[16][64];
    __shared__ __align__(16) float Xs2[16][64];
    float acc[4][4] = {};
    for (int k0 = 0; k0 < C; k0 += 16) {
        #pragma unroll
        for (int e = 0; e < 4; e++) {
            int idx = e * 256 + tid;
            int m = idx & 63, kk = idx >> 6;
            Ws[kk][m] = pw_w[(co0 + m) * C + (k0 + kk)];
        }
        #pragma unroll
        for (int e = 0; e < 4; e++) {
            int idx = e * 256 + tid;
            int nn = idx & 63, kk = idx >> 6;
            int ci = k0 + kk;
            int n = n0 + nn;
            int b = n / P, p = n - b * P;
            int oh = p / OUT_H, ow = p - oh * OUT_H;
            const float* ip = in + (((size_t)b * C + ci) * IN_H + oh) * IN_H + ow;
            const float* wp = dw_w + ci * 9;
            float s = 0.f;
            #pragma unroll
            for (int dy = 0; dy < 3; dy++)
                #pragma unroll
                for (int dx = 0; dx < 3; dx++)
                    s = fmaf(ip[dy * IN_H + dx], wp[dy * 3 + dx], s);
            float inv = bn1[ci] * rsqrtf(bn1[3 * C + ci] + EPS);
            float y = s * inv + (bn1[C + ci] - bn1[2 * C + ci] * inv);
            Xs2[kk][nn] = fminf(fmaxf(y, 0.f), 6.f);
        }
        __syncthreads();
        #pragma unroll
        for (int kk = 0; kk < 16; kk++) {
            float4 av = *reinterpret_cast<const float4*>(&Ws[kk][ty * 4]);
            float4 bv = *reinterpret_cast<const float4*>(&Xs2[kk][tx * 4]);
            float a[4] = {av.x, av.y, av.z, av.w};
            float bb[4] = {bv.x, bv.y, bv.z, bv.w};
            #pragma unroll
            for (int i = 0; i < 4; i++)
                #pragma unroll
                for (int j = 0; j < 4; j++)
                    acc[i][j] = fmaf(a[i], bb[j], acc[i][j]);
        }
        __syncthreads();
    }
    #pragma unroll
    for (int i = 0; i < 4; i++) {
        int co = co0 + ty * 4 + i;
        float inv = bn2[co] * rsqrtf(bn2[3 * C + co] + EPS);
        float sh  = (bn2[C + co] - bn2[2 * C + co] * inv) + pw_b[co] * inv;
        int n = n0 + tx * 4;
        #pragma unroll
        for (int j = 0; j < 4; j++) {
            int nj = n + j;
            int bj2 = nj / P, pj2 = nj - bj2 * P;
            out[((size_t)bj2 * C + co) * P + pj2] = acc[i][j] * inv + sh;
        }
    }
}

extern "C" void kernel_launch(void* const* d_in, const int* in_sizes, int n_in,
                              void* d_out, int out_size, void* d_ws, size_t ws_size,
                              hipStream_t stream) {
    const float* kernel = (const float*)d_in[0];
    const float* search = (const float*)d_in[1];
    const float* k_dw_w = (const float*)d_in[2];
    const float* k_bn1  = (const float*)d_in[3];
    const float* k_pw_w = (const float*)d_in[4];
    const float* k_pw_b = (const float*)d_in[5];
    const float* k_bn2  = (const float*)d_in[6];
    const float* s_dw_w = (const float*)d_in[7];
    const float* s_bn1  = (const float*)d_in[8];
    const float* s_pw_w = (const float*)d_in[9];
    const float* s_pw_b = (const float*)d_in[10];
    const float* s_bn2  = (const float*)d_in[11];

    constexpr size_t SB_B  = (size_t)NSG * C * 4;      // 110,231,552
    constexpr size_t KB_B  = (size_t)NKG * C * 4;      //   3,276,800
    constexpr size_t X3S_B = (size_t)NSG * 512;        //  55,115,776 per plane
    constexpr size_t X3K_B = (size_t)NKG * 512;        //   1,638,400 per plane
    constexpr size_t W_B   = (size_t)C * 512 * 2;      //     262,144
    constexpr size_t NEED  = SB_B + KB_B + 2 * X3S_B + 2 * X3K_B + 2 * W_B;

    if (ws_size >= NEED) {
        char* base = (char*)d_ws;
        float* Sb  = (float*)base;  base += SB_B;
        float* Kb  = (float*)base;  base += KB_B;
        u16* X3hs  = (u16*)base;    base += X3S_B;
        u16* X3ls  = (u16*)base;    base += X3S_B;
        u16* X3hk  = (u16*)base;    base += X3K_B;
        u16* X3lk  = (u16*)base;    base += X3K_B;
        u16* WcS   = (u16*)base;    base += W_B;
        u16* WcK   = (u16*)base;

        wprep<<<dim3(256), dim3(256), 0, stream>>>(s_pw_w, k_pw_w, WcS, WcK);
        dw_pass2<31, 8><<<dim3(B, 32), dim3(256), 0, stream>>>(search, s_dw_w, s_bn1, X3hs, X3ls);
        dw_pass2<7, 32><<<dim3(B, 8), dim3(256), 0, stream>>>(kernel, k_dw_w, k_bn1, X3hk, X3lk);
        gemm2<841><<<dim3(NSG / 128), dim3(512), 0, stream>>>(X3hs, X3ls, WcS, s_pw_b, s_bn2, Sb);
        gemm2<25><<<dim3(NKG / 128), dim3(512), 0, stream>>>(X3hk, X3lk, WcK, k_pw_b, k_bn2, Kb);
        xcorr2<<<dim3((B * C + 9) / 10), dim3(256), 0, stream>>>(Sb, Kb, (float*)d_out);
    } else {
        float* s_buf = (float*)d_ws;
        float* k_buf = s_buf + (size_t)B * C * 29 * 29;
        branch_fallback<7><<<dim3(50, 4), dim3(256), 0, stream>>>(
            kernel, k_dw_w, k_bn1, k_pw_w, k_pw_b, k_bn2, k_buf);
        branch_fallback<31><<<dim3(1682, 4), dim3(256), 0, stream>>>(
            search, s_dw_w, s_bn1, s_pw_w, s_pw_b, s_bn2, s_buf);
        xcorr2<<<dim3((B * C + 9) / 10), dim3(256), 0, stream>>>(s_buf, k_buf, (float*)d_out);
    }
}

// Round 6
// 206.203 us; speedup vs baseline: 3.3469x; 1.0686x over previous
//
#include <hip/hip_runtime.h>

constexpr int B = 128, C = 256;
constexpr float EPS = 1e-5f;
constexpr int NSG = B * 841;   // 107648 search GEMM columns
constexpr int NKG = B * 25;    // 3200 kernel GEMM columns

typedef unsigned short u16;
typedef short short8 __attribute__((ext_vector_type(8)));
typedef u16 u16x8 __attribute__((ext_vector_type(8)));
typedef float f32x4 __attribute__((ext_vector_type(4)));

__device__ __forceinline__ u16 bf16_rne(float x) {
    unsigned u = __builtin_bit_cast(unsigned, x);
    return (u16)((u + 0x7FFFu + ((u >> 16) & 1u)) >> 16);
}

#define GLOAD16(g, l)                                                              \
    __builtin_amdgcn_global_load_lds(                                              \
        (const __attribute__((address_space(1))) unsigned int*)(g),                \
        (__attribute__((address_space(3))) unsigned int*)(l), 16, 0, 0)

// ---------------------------------------------------------------------------
// W prep: fp32 (C,C) -> interleaved hi/lo bf16: Wc[co][kb][ {hi:32 | lo:32} ]
// ---------------------------------------------------------------------------
__global__ __launch_bounds__(256)
void wprep(const float* __restrict__ ws, const float* __restrict__ wk,
           u16* __restrict__ WcS, u16* __restrict__ WcK) {
    int i = blockIdx.x * 256 + threadIdx.x;     // co*256 + k
    int co = i >> 8, k = i & 255;
    size_t o = (size_t)co * 512 + (k >> 5) * 64 + (k & 31);
    {
        float a = ws[i];
        u16 h = bf16_rne(a);
        float hf = __builtin_bit_cast(float, (unsigned)h << 16);
        WcS[o] = h; WcS[o + 32] = bf16_rne(a - hf);
    }
    {
        float a = wk[i];
        u16 h = bf16_rne(a);
        float hf = __builtin_bit_cast(float, (unsigned)h << 16);
        WcK[o] = h; WcK[o + 32] = bf16_rne(a - hf);
    }
}

// ---------------------------------------------------------------------------
// dw_pass3: depthwise 3x3 + BN1 + ReLU6 -> X3h/X3l planes [kc][n][8 u16].
// v3: contiguous float4 staging (no swizzle scatter), direct b32 compute
// reads (stride-31 rows -> conflict-free), transpose/output kept from r5.
// ---------------------------------------------------------------------------
template<int IN_H, int CG>
__global__ __launch_bounds__(256)
void dw_pass3(const float* __restrict__ in, const float* __restrict__ dw_w,
              const float* __restrict__ bn1,
              u16* __restrict__ X3h, u16* __restrict__ X3l) {
    constexpr int OUT_H = IN_H - 2, ON = OUT_H * OUT_H, IHW = IN_H * IN_H;
    constexpr int NSTRIP = (OUT_H + 7) / 8;       // 4 or 1
    constexpr int NFLT = CG * IHW;                // 7688 / 1568
    constexpr int NF4 = NFLT / 4;                 // exact
    constexpr int SUBS = CG / 8;
    constexpr int NSP = B * ON;
    constexpr unsigned SM_IN = (NFLT + 16) * 4;   // +pad for tail over-read
    constexpr unsigned SM_XT = 2u * ON * CG * 2;
    constexpr unsigned SMSZ = SM_IN > SM_XT ? SM_IN : SM_XT;
    __shared__ __align__(16) char SMEM[SMSZ];
    float* S = (float*)SMEM;
    u16* xt = (u16*)SMEM;   // reused after compute: [2][ON][CG]

    const int tid = threadIdx.x;
    const int b = blockIdx.x, g = blockIdx.y;
    const int ci0 = g * CG;
    const float* src = in + ((size_t)b * C + ci0) * IHW;

    // ---- stage input: straight contiguous float4 copy
    for (int q = tid; q < NF4; q += 256)
        ((float4*)S)[q] = ((const float4*)src)[q];
    __syncthreads();

    // ---- compute: task = (channel cl, output row oh)
    const bool active = tid < CG * OUT_H;
    int cl = 0, oh = 0;
    if (active) { cl = tid / OUT_H; oh = tid - cl * OUT_H; }
    unsigned outv[NSTRIP][8];
    if (active) {
        const int ci = ci0 + cl;
        float wreg[9];
        #pragma unroll
        for (int q = 0; q < 9; ++q) wreg[q] = dw_w[ci * 9 + q];
        const float inv = bn1[ci] * rsqrtf(bn1[3 * C + ci] + EPS);
        const float shv = bn1[C + ci] - bn1[2 * C + ci] * inv;
        #pragma unroll
        for (int s = 0; s < NSTRIP; ++s) {
            float res[8] = {0.f, 0.f, 0.f, 0.f, 0.f, 0.f, 0.f, 0.f};
            #pragma unroll
            for (int dy = 0; dy < 3; ++dy) {
                const float* r = S + cl * IHW + (oh + dy) * IN_H + s * 8;
                float x[10];
                #pragma unroll
                for (int j = 0; j < 10; ++j) x[j] = r[j];
                #pragma unroll
                for (int o = 0; o < 8; ++o)
                    res[o] = fmaf(x[o], wreg[dy * 3],
                              fmaf(x[o + 1], wreg[dy * 3 + 1],
                               fmaf(x[o + 2], wreg[dy * 3 + 2], res[o])));
            }
            #pragma unroll
            for (int o = 0; o < 8; ++o) {
                float y = res[o] * inv + shv;
                y = fminf(fmaxf(y, 0.f), 6.f);
                u16 h = bf16_rne(y);
                float hf = __builtin_bit_cast(float, (unsigned)h << 16);
                outv[s][o] = (unsigned)h | ((unsigned)bf16_rne(y - hf) << 16);
            }
        }
    }
    __syncthreads();   // input LDS now free

    // ---- transpose: scatter into xt[plane][n][cl]
    if (active) {
        #pragma unroll
        for (int s = 0; s < NSTRIP; ++s) {
            const int ow0 = s * 8;
            #pragma unroll
            for (int o = 0; o < 8; ++o) {
                if (ow0 + o < OUT_H) {
                    int n = oh * OUT_H + ow0 + o;
                    xt[(size_t)n * CG + cl]        = (u16)outv[s][o];
                    xt[((size_t)ON + n) * CG + cl] = (u16)(outv[s][o] >> 16);
                }
            }
        }
    }
    __syncthreads();

    // ---- coalesced 16B writes to the planes
    constexpr int NCH = 2 * ON * SUBS;
    for (int q = tid; q < NCH; q += 256) {
        int plane = q / (ON * SUBS);
        int r2 = q - plane * (ON * SUBS);
        int sub = r2 / ON, n = r2 - sub * ON;
        u16x8 v = *(const u16x8*)&xt[((size_t)plane * ON + n) * CG + sub * 8];
        u16* dst = (plane ? X3l : X3h) +
                   ((size_t)(g * SUBS + sub) * NSP + (size_t)b * ON + n) * 8;
        *(u16x8*)dst = v;
    }
}

// ---------------------------------------------------------------------------
// gemm3: out[co,n] = BN2( sum_ci W[co,ci]*X[ci,n] + bias ), split-bf16 MFMA.
// BM=128 (grid.y = co half), BN=128, BK=32; LDS 64KB -> 2 blocks/CU for
// cross-block latency hiding; double-buffered, counted vmcnt(8).
// ---------------------------------------------------------------------------
template<int PQ>
__global__ __launch_bounds__(256)
void gemm3(const u16* __restrict__ X3h, const u16* __restrict__ X3l,
           const u16* __restrict__ Wc, const float* __restrict__ pw_b,
           const float* __restrict__ bn2, float* __restrict__ out) {
    constexpr int NSP = B * PQ;
    __shared__ u16 XS[2][128 * 64];   // 16KB each: 128 n-rows x [32 hi|32 lo]
    __shared__ u16 WS[2][128 * 64];   // 16KB each: 128 co-rows x [32 hi|32 lo]

    const int tid = threadIdx.x;
    const int lane = tid & 63, wave = tid >> 6;    // 4 waves
    const int wm = wave >> 1, wn = wave & 1;
    const int n0 = blockIdx.x * 128;
    const int co0 = blockIdx.y * 128;

    auto stage = [&](int d, int t) {
        #pragma unroll
        for (int ii = 0; ii < 4; ++ii) {           // W: 1024 chunks
            int c = (wave * 4 + ii) * 64 + lane;
            int row = c >> 3, k16 = c & 7;
            int sb = (k16 * 16) ^ ((row & 7) << 4);
            GLOAD16(Wc + (size_t)(co0 + row) * 512 + t * 64 + (sb >> 1),
                    (char*)WS[d] + c * 16);
        }
        #pragma unroll
        for (int ii = 0; ii < 4; ++ii) {           // X: 1024 chunks
            int c = (wave * 4 + ii) * 64 + lane;
            int row = c >> 3, m = c & 7;
            int u = m ^ (row & 7);                 // unswizzled chunk
            const u16* pl = (u < 4) ? X3h : X3l;
            int kc = t * 4 + (u & 3);
            GLOAD16(pl + ((size_t)kc * NSP + n0 + row) * 8, (char*)XS[d] + c * 16);
        }
    };

    f32x4 acc[4][4] = {};
    stage(0, 0);

    for (int t = 0; t < 8; ++t) {
        const int d = t & 1;
        if (t < 7) {
            stage(d ^ 1, t + 1);
            asm volatile("s_waitcnt vmcnt(8)" ::: "memory");   // buf d done, next in flight
        } else {
            asm volatile("s_waitcnt vmcnt(0)" ::: "memory");
        }
        __builtin_amdgcn_s_barrier();
        __builtin_amdgcn_sched_barrier(0);

        const u16* xs = XS[d];
        const u16* wsp = WS[d];
        const int kb = (lane >> 4) * 16;
        short8 bxh[4], bxl[4], aw[4];
        #pragma unroll
        for (int j = 0; j < 4; ++j) {
            int row = wn * 64 + j * 16 + (lane & 15);
            int off = row * 128 + (kb ^ ((row & 7) << 4));
            bxh[j] = *(const short8*)((const char*)xs + off);
            bxl[j] = *(const short8*)((const char*)xs + (off ^ 64));
        }
        #pragma unroll
        for (int i = 0; i < 4; ++i) {
            int row = wm * 64 + i * 16 + (lane & 15);
            aw[i] = *(const short8*)((const char*)wsp + (row * 128 + (kb ^ ((row & 7) << 4))));
        }
        #pragma unroll
        for (int i = 0; i < 4; ++i)
            #pragma unroll
            for (int j = 0; j < 4; ++j) {
                acc[i][j] = __builtin_amdgcn_mfma_f32_16x16x32_bf16(aw[i], bxh[j], acc[i][j], 0, 0, 0);
                acc[i][j] = __builtin_amdgcn_mfma_f32_16x16x32_bf16(aw[i], bxl[j], acc[i][j], 0, 0, 0);
            }
        #pragma unroll
        for (int i = 0; i < 4; ++i) {
            int row = wm * 64 + i * 16 + (lane & 15);
            aw[i] = *(const short8*)((const char*)wsp + ((row * 128 + (kb ^ ((row & 7) << 4))) ^ 64));
        }
        #pragma unroll
        for (int i = 0; i < 4; ++i)
            #pragma unroll
            for (int j = 0; j < 4; ++j)
                acc[i][j] = __builtin_amdgcn_mfma_f32_16x16x32_bf16(aw[i], bxh[j], acc[i][j], 0, 0, 0);

        asm volatile("s_waitcnt lgkmcnt(0)" ::: "memory");
        __builtin_amdgcn_sched_barrier(0);
        __builtin_amdgcn_s_barrier();   // raw barrier: vmem prefetch stays in flight
    }

    // ---- epilogue: bias + BN2, fp32 store (layout validated r2/r4/r5)
    int bj[4], pj[4];
    #pragma unroll
    for (int j = 0; j < 4; ++j) {
        int nn = n0 + wn * 64 + j * 16 + (lane & 15);
        bj[j] = nn / PQ; pj[j] = nn - bj[j] * PQ;
    }
    #pragma unroll
    for (int i = 0; i < 4; ++i) {
        #pragma unroll
        for (int r = 0; r < 4; ++r) {
            int co = co0 + wm * 64 + i * 16 + (lane >> 4) * 4 + r;
            float inv = bn2[co] * rsqrtf(bn2[3 * C + co] + EPS);
            float sh  = bn2[C + co] - bn2[2 * C + co] * inv + pw_b[co] * inv;
            #pragma unroll
            for (int j = 0; j < 4; ++j)
                out[((size_t)bj[j] * C + co) * PQ + pj[j]] = acc[i][j][r] * inv + sh;
        }
    }
}

// ---------------------------------------------------------------------------
// xcorr: 10 (b,c) pairs per block; 25 threads/pair, 5x5 output tile each
// ---------------------------------------------------------------------------
__global__ __launch_bounds__(256)
void xcorr2(const float* __restrict__ s, const float* __restrict__ k,
            float* __restrict__ out) {
    const int bc0 = blockIdx.x * 10;
    const int nbc = min(10, B * C - bc0);
    __shared__ float ss[10 * 841];
    __shared__ float ks[10 * 25];
    const int tid = threadIdx.x;
    for (int i = tid; i < nbc * 841; i += 256) ss[i] = s[(size_t)bc0 * 841 + i];
    for (int i = tid; i < nbc * 25; i += 256) ks[i] = k[(size_t)bc0 * 25 + i];
    __syncthreads();

    const int lb = tid / 25, lt = tid - lb * 25;
    if (lb >= nbc) return;
    const int ohg = lt / 5, owg = lt - ohg * 5;
    const float* sp = ss + lb * 841 + (ohg * 5) * 29 + owg * 5;
    float kk[25];
    #pragma unroll
    for (int q = 0; q < 25; ++q) kk[q] = ks[lb * 25 + q];

    float acc[5][5] = {};
    #pragma unroll
    for (int ir = 0; ir < 9; ++ir) {
        float row[9];
        #pragma unroll
        for (int j = 0; j < 9; ++j) row[j] = sp[ir * 29 + j];
        #pragma unroll
        for (int oi = 0; oi < 5; ++oi) {
            int ki = ir - oi;
            if (ki < 0 || ki > 4) continue;
            #pragma unroll
            for (int oj = 0; oj < 5; ++oj)
                #pragma unroll
                for (int kj = 0; kj < 5; ++kj)
                    acc[oi][oj] = fmaf(row[oj + kj], kk[ki * 5 + kj], acc[oi][oj]);
        }
    }
    float* op = out + (size_t)(bc0 + lb) * 625;
    #pragma unroll
    for (int oi = 0; oi < 5; ++oi)
        #pragma unroll
        for (int oj = 0; oj < 5; ++oj)
            op[(ohg * 5 + oi) * 25 + owg * 5 + oj] = acc[oi][oj];
}

// ---------------------------------------------------------------------------
// Fallback (round-1 fp32 path) in case ws_size is too small
// ---------------------------------------------------------------------------
template<int IN_H>
__global__ __launch_bounds__(256)
void branch_fallback(const float* __restrict__ in, const float* __restrict__ dw_w,
                     const float* __restrict__ bn1, const float* __restrict__ pw_w,
                     const float* __restrict__ pw_b, const float* __restrict__ bn2,
                     float* __restrict__ out) {
    constexpr int OUT_H = IN_H - 2;
    constexpr int P = OUT_H * OUT_H;
    const int n0  = blockIdx.x * 64;
    const int co0 = blockIdx.y * 64;
    const int tid = threadIdx.x;
    const int tx = tid & 15, ty = tid >> 4;
    __shared__ __align__(16) float Ws[16][64];
    __shared__ __align__(16) float Xs2[16][64];
    float acc[4][4] = {};
    for (int k0 = 0; k0 < C; k0 += 16) {
        #pragma unroll
        for (int e = 0; e < 4; e++) {
            int idx = e * 256 + tid;
            int m = idx & 63, kk = idx >> 6;
            Ws[kk][m] = pw_w[(co0 + m) * C + (k0 + kk)];
        }
        #pragma unroll
        for (int e = 0; e < 4; e++) {
            int idx = e * 256 + tid;
            int nn = idx & 63, kk = idx >> 6;
            int ci = k0 + kk;
            int n = n0 + nn;
            int b = n / P, p = n - b * P;
            int oh = p / OUT_H, ow = p - oh * OUT_H;
            const float* ip = in + (((size_t)b * C + ci) * IN_H + oh) * IN_H + ow;
            const float* wp = dw_w + ci * 9;
            float s = 0.f;
            #pragma unroll
            for (int dy = 0; dy < 3; dy++)
                #pragma unroll
                for (int dx = 0; dx < 3; dx++)
                    s = fmaf(ip[dy * IN_H + dx], wp[dy * 3 + dx], s);
            float inv = bn1[ci] * rsqrtf(bn1[3 * C + ci] + EPS);
            float y = s * inv + (bn1[C + ci] - bn1[2 * C + ci] * inv);
            Xs2[kk][nn] = fminf(fmaxf(y, 0.f), 6.f);
        }
        __syncthreads();
        #pragma unroll
        for (int kk = 0; kk < 16; kk++) {
            float4 av = *reinterpret_cast<const float4*>(&Ws[kk][ty * 4]);
            float4 bv = *reinterpret_cast<const float4*>(&Xs2[kk][tx * 4]);
            float a[4] = {av.x, av.y, av.z, av.w};
            float bb[4] = {bv.x, bv.y, bv.z, bv.w};
            #pragma unroll
            for (int i = 0; i < 4; i++)
                #pragma unroll
                for (int j = 0; j < 4; j++)
                    acc[i][j] = fmaf(a[i], bb[j], acc[i][j]);
        }
        __syncthreads();
    }
    #pragma unroll
    for (int i = 0; i < 4; i++) {
        int co = co0 + ty * 4 + i;
        float inv = bn2[co] * rsqrtf(bn2[3 * C + co] + EPS);
        float sh  = (bn2[C + co] - bn2[2 * C + co] * inv) + pw_b[co] * inv;
        int n = n0 + tx * 4;
        #pragma unroll
        for (int j = 0; j < 4; j++) {
            int nj = n + j;
            int bj2 = nj / P, pj2 = nj - bj2 * P;
            out[((size_t)bj2 * C + co) * P + pj2] = acc[i][j] * inv + sh;
        }
    }
}

extern "C" void kernel_launch(void* const* d_in, const int* in_sizes, int n_in,
                              void* d_out, int out_size, void* d_ws, size_t ws_size,
                              hipStream_t stream) {
    const float* kernel = (const float*)d_in[0];
    const float* search = (const float*)d_in[1];
    const float* k_dw_w = (const float*)d_in[2];
    const float* k_bn1  = (const float*)d_in[3];
    const float* k_pw_w = (const float*)d_in[4];
    const float* k_pw_b = (const float*)d_in[5];
    const float* k_bn2  = (const float*)d_in[6];
    const float* s_dw_w = (const float*)d_in[7];
    const float* s_bn1  = (const float*)d_in[8];
    const float* s_pw_w = (const float*)d_in[9];
    const float* s_pw_b = (const float*)d_in[10];
    const float* s_bn2  = (const float*)d_in[11];

    constexpr size_t SB_B  = (size_t)NSG * C * 4;      // 110,231,552
    constexpr size_t KB_B  = (size_t)NKG * C * 4;      //   3,276,800
    constexpr size_t X3S_B = (size_t)NSG * 512;        //  55,115,776 per plane
    constexpr size_t X3K_B = (size_t)NKG * 512;        //   1,638,400 per plane
    constexpr size_t W_B   = (size_t)C * 512 * 2;      //     262,144
    constexpr size_t NEED  = SB_B + KB_B + 2 * X3S_B + 2 * X3K_B + 2 * W_B;

    if (ws_size >= NEED) {
        char* base = (char*)d_ws;
        float* Sb  = (float*)base;  base += SB_B;
        float* Kb  = (float*)base;  base += KB_B;
        u16* X3hs  = (u16*)base;    base += X3S_B;
        u16* X3ls  = (u16*)base;    base += X3S_B;
        u16* X3hk  = (u16*)base;    base += X3K_B;
        u16* X3lk  = (u16*)base;    base += X3K_B;
        u16* WcS   = (u16*)base;    base += W_B;
        u16* WcK   = (u16*)base;

        wprep<<<dim3(256), dim3(256), 0, stream>>>(s_pw_w, k_pw_w, WcS, WcK);
        dw_pass3<31, 8><<<dim3(B, 32), dim3(256), 0, stream>>>(search, s_dw_w, s_bn1, X3hs, X3ls);
        dw_pass3<7, 32><<<dim3(B, 8), dim3(256), 0, stream>>>(kernel, k_dw_w, k_bn1, X3hk, X3lk);
        gemm3<841><<<dim3(NSG / 128, 2), dim3(256), 0, stream>>>(X3hs, X3ls, WcS, s_pw_b, s_bn2, Sb);
        gemm3<25><<<dim3(NKG / 128, 2), dim3(256), 0, stream>>>(X3hk, X3lk, WcK, k_pw_b, k_bn2, Kb);
        xcorr2<<<dim3((B * C + 9) / 10), dim3(256), 0, stream>>>(Sb, Kb, (float*)d_out);
    } else {
        float* s_buf = (float*)d_ws;
        float* k_buf = s_buf + (size_t)B * C * 29 * 29;
        branch_fallback<7><<<dim3(50, 4), dim3(256), 0, stream>>>(
            kernel, k_dw_w, k_bn1, k_pw_w, k_pw_b, k_bn2, k_buf);
        branch_fallback<31><<<dim3(1682, 4), dim3(256), 0, stream>>>(
            search, s_dw_w, s_bn1, s_pw_w, s_pw_b, s_bn2, s_buf);
        xcorr2<<<dim3((B * C + 9) / 10), dim3(256), 0, stream>>>(s_buf, k_buf, (float*)d_out);
    }
}

// Round 7
// 198.721 us; speedup vs baseline: 3.4729x; 1.0377x over previous
//
#include <hip/hip_runtime.h>

constexpr int B = 128, C = 256;
constexpr float EPS = 1e-5f;
constexpr int NSG = B * 841;   // 107648 search GEMM columns
constexpr int NKG = B * 25;    // 3200 kernel GEMM columns

typedef unsigned short u16;
typedef short short8 __attribute__((ext_vector_type(8)));
typedef u16 u16x8 __attribute__((ext_vector_type(8)));
typedef float f32x4 __attribute__((ext_vector_type(4)));

__device__ __forceinline__ u16 bf16_rne(float x) {
    unsigned u = __builtin_bit_cast(unsigned, x);
    return (u16)((u + 0x7FFFu + ((u >> 16) & 1u)) >> 16);
}

// ---------------------------------------------------------------------------
// wprep2: fp32 (C,C) -> frag-major hi/lo bf16.
// Wt layout: hi at [0,65536), lo at [65536,131072) u16.
// Wt[(t*16+cg)*64 + lane][8]: lane l -> co = cg*16+(l&15), k = t*32+(l>>4)*8+e.
// A-fragment of mfma_16x16x32 loads as ONE coalesced dwordx4 per lane.
// ---------------------------------------------------------------------------
__global__ __launch_bounds__(256)
void wprep2(const float* __restrict__ ws, const float* __restrict__ wk,
            u16* __restrict__ WtS, u16* __restrict__ WtK) {
    int i = blockIdx.x * 256 + threadIdx.x;   // co*256 + k over 65536
    int co = i >> 8, k = i & 255;
    int t = k >> 5, cg = co >> 4;
    int lane = ((k >> 3) & 3) * 16 + (co & 15);
    int e = k & 7;
    size_t o = ((size_t)(t * 16 + cg) * 64 + lane) * 8 + e;
    {
        float a = ws[i];
        u16 h = bf16_rne(a);
        float hf = __builtin_bit_cast(float, (unsigned)h << 16);
        WtS[o] = h; WtS[65536 + o] = bf16_rne(a - hf);
    }
    {
        float a = wk[i];
        u16 h = bf16_rne(a);
        float hf = __builtin_bit_cast(float, (unsigned)h << 16);
        WtK[o] = h; WtK[65536 + o] = bf16_rne(a - hf);
    }
}

// ---------------------------------------------------------------------------
// dw_pass3: depthwise 3x3 + BN1 + ReLU6 -> X3h/X3l planes [kc][n][8 u16].
// (unchanged from r6: contiguous staging, direct b32 reads, LDS transpose)
// ---------------------------------------------------------------------------
template<int IN_H, int CG>
__global__ __launch_bounds__(256)
void dw_pass3(const float* __restrict__ in, const float* __restrict__ dw_w,
              const float* __restrict__ bn1,
              u16* __restrict__ X3h, u16* __restrict__ X3l) {
    constexpr int OUT_H = IN_H - 2, ON = OUT_H * OUT_H, IHW = IN_H * IN_H;
    constexpr int NSTRIP = (OUT_H + 7) / 8;
    constexpr int NFLT = CG * IHW;
    constexpr int NF4 = NFLT / 4;
    constexpr int SUBS = CG / 8;
    constexpr int NSP = B * ON;
    constexpr unsigned SM_IN = (NFLT + 16) * 4;
    constexpr unsigned SM_XT = 2u * ON * CG * 2;
    constexpr unsigned SMSZ = SM_IN > SM_XT ? SM_IN : SM_XT;
    __shared__ __align__(16) char SMEM[SMSZ];
    float* S = (float*)SMEM;
    u16* xt = (u16*)SMEM;

    const int tid = threadIdx.x;
    const int b = blockIdx.x, g = blockIdx.y;
    const int ci0 = g * CG;
    const float* src = in + ((size_t)b * C + ci0) * IHW;

    for (int q = tid; q < NF4; q += 256)
        ((float4*)S)[q] = ((const float4*)src)[q];
    __syncthreads();

    const bool active = tid < CG * OUT_H;
    int cl = 0, oh = 0;
    if (active) { cl = tid / OUT_H; oh = tid - cl * OUT_H; }
    unsigned outv[NSTRIP][8];
    if (active) {
        const int ci = ci0 + cl;
        float wreg[9];
        #pragma unroll
        for (int q = 0; q < 9; ++q) wreg[q] = dw_w[ci * 9 + q];
        const float inv = bn1[ci] * rsqrtf(bn1[3 * C + ci] + EPS);
        const float shv = bn1[C + ci] - bn1[2 * C + ci] * inv;
        #pragma unroll
        for (int s = 0; s < NSTRIP; ++s) {
            float res[8] = {0.f, 0.f, 0.f, 0.f, 0.f, 0.f, 0.f, 0.f};
            #pragma unroll
            for (int dy = 0; dy < 3; ++dy) {
                const float* r = S + cl * IHW + (oh + dy) * IN_H + s * 8;
                float x[10];
                #pragma unroll
                for (int j = 0; j < 10; ++j) x[j] = r[j];
                #pragma unroll
                for (int o = 0; o < 8; ++o)
                    res[o] = fmaf(x[o], wreg[dy * 3],
                              fmaf(x[o + 1], wreg[dy * 3 + 1],
                               fmaf(x[o + 2], wreg[dy * 3 + 2], res[o])));
            }
            #pragma unroll
            for (int o = 0; o < 8; ++o) {
                float y = res[o] * inv + shv;
                y = fminf(fmaxf(y, 0.f), 6.f);
                u16 h = bf16_rne(y);
                float hf = __builtin_bit_cast(float, (unsigned)h << 16);
                outv[s][o] = (unsigned)h | ((unsigned)bf16_rne(y - hf) << 16);
            }
        }
    }
    __syncthreads();

    if (active) {
        #pragma unroll
        for (int s = 0; s < NSTRIP; ++s) {
            const int ow0 = s * 8;
            #pragma unroll
            for (int o = 0; o < 8; ++o) {
                if (ow0 + o < OUT_H) {
                    int n = oh * OUT_H + ow0 + o;
                    xt[(size_t)n * CG + cl]        = (u16)outv[s][o];
                    xt[((size_t)ON + n) * CG + cl] = (u16)(outv[s][o] >> 16);
                }
            }
        }
    }
    __syncthreads();

    constexpr int NCH = 2 * ON * SUBS;
    for (int q = tid; q < NCH; q += 256) {
        int plane = q / (ON * SUBS);
        int r2 = q - plane * (ON * SUBS);
        int sub = r2 / ON, n = r2 - sub * ON;
        u16x8 v = *(const u16x8*)&xt[((size_t)plane * ON + n) * CG + sub * 8];
        u16* dst = (plane ? X3l : X3h) +
                   ((size_t)(g * SUBS + sub) * NSP + (size_t)b * ON + n) * 8;
        *(u16x8*)dst = v;
    }
}

// ---------------------------------------------------------------------------
// gemm4: LDS-free, barrier-free MFMA GEMM with direct global->VGPR frags.
// Block = 256 thr = 4 free-running waves; wave w owns co strip w*64..w*64+63
// at n0 = blockIdx.x*64. Per K=32 step: 16 coalesced dwordx4 loads + 48 MFMA.
// W from frag-major Wt (L2-hot); X from X3 planes (frag-native layout).
// ---------------------------------------------------------------------------
template<int PQ>
__global__ __launch_bounds__(256)
void gemm4(const u16* __restrict__ X3h, const u16* __restrict__ X3l,
           const u16* __restrict__ Wt, const float* __restrict__ pw_b,
           const float* __restrict__ bn2, float* __restrict__ out) {
    constexpr int NSP = B * PQ;
    const int lane = threadIdx.x & 63, wave = threadIdx.x >> 6;
    const int lh = lane >> 4, ll = lane & 15;
    const int n0 = blockIdx.x * 64;
    const u16* Wth = Wt;
    const u16* Wtl = Wt + 65536;

    f32x4 acc[4][4] = {};

    #pragma unroll 1
    for (int t = 0; t < 8; ++t) {
        short8 awh[4], awl[4], bxh[4], bxl[4];
        #pragma unroll
        for (int j = 0; j < 4; ++j) {
            size_t off = ((size_t)(t * 4 + lh) * NSP + n0 + j * 16 + ll) * 8;
            bxh[j] = *(const short8*)(X3h + off);
            bxl[j] = *(const short8*)(X3l + off);
        }
        #pragma unroll
        for (int i = 0; i < 4; ++i) {
            int cg = wave * 4 + i;
            size_t off = ((size_t)(t * 16 + cg) * 64 + lane) * 8;
            awh[i] = *(const short8*)(Wth + off);
            awl[i] = *(const short8*)(Wtl + off);
        }
        #pragma unroll
        for (int i = 0; i < 4; ++i)
            #pragma unroll
            for (int j = 0; j < 4; ++j) {
                acc[i][j] = __builtin_amdgcn_mfma_f32_16x16x32_bf16(awh[i], bxh[j], acc[i][j], 0, 0, 0);
                acc[i][j] = __builtin_amdgcn_mfma_f32_16x16x32_bf16(awh[i], bxl[j], acc[i][j], 0, 0, 0);
                acc[i][j] = __builtin_amdgcn_mfma_f32_16x16x32_bf16(awl[i], bxh[j], acc[i][j], 0, 0, 0);
            }
    }

    // ---- epilogue: bias + BN2, fp32 store (layout validated r2..r6)
    int bj[4], pj[4];
    #pragma unroll
    for (int j = 0; j < 4; ++j) {
        int nn = n0 + j * 16 + ll;
        bj[j] = nn / PQ; pj[j] = nn - bj[j] * PQ;
    }
    #pragma unroll
    for (int i = 0; i < 4; ++i) {
        #pragma unroll
        for (int r = 0; r < 4; ++r) {
            int co = wave * 64 + i * 16 + lh * 4 + r;
            float inv = bn2[co] * rsqrtf(bn2[3 * C + co] + EPS);
            float sh  = bn2[C + co] - bn2[2 * C + co] * inv + pw_b[co] * inv;
            #pragma unroll
            for (int j = 0; j < 4; ++j)
                out[((size_t)bj[j] * C + co) * PQ + pj[j]] = acc[i][j][r] * inv + sh;
        }
    }
}

// ---------------------------------------------------------------------------
// xcorr: 10 (b,c) pairs per block; 25 threads/pair, 5x5 output tile each
// ---------------------------------------------------------------------------
__global__ __launch_bounds__(256)
void xcorr2(const float* __restrict__ s, const float* __restrict__ k,
            float* __restrict__ out) {
    const int bc0 = blockIdx.x * 10;
    const int nbc = min(10, B * C - bc0);
    __shared__ float ss[10 * 841];
    __shared__ float ks[10 * 25];
    const int tid = threadIdx.x;
    for (int i = tid; i < nbc * 841; i += 256) ss[i] = s[(size_t)bc0 * 841 + i];
    for (int i = tid; i < nbc * 25; i += 256) ks[i] = k[(size_t)bc0 * 25 + i];
    __syncthreads();

    const int lb = tid / 25, lt = tid - lb * 25;
    if (lb >= nbc) return;
    const int ohg = lt / 5, owg = lt - ohg * 5;
    const float* sp = ss + lb * 841 + (ohg * 5) * 29 + owg * 5;
    float kk[25];
    #pragma unroll
    for (int q = 0; q < 25; ++q) kk[q] = ks[lb * 25 + q];

    float acc[5][5] = {};
    #pragma unroll
    for (int ir = 0; ir < 9; ++ir) {
        float row[9];
        #pragma unroll
        for (int j = 0; j < 9; ++j) row[j] = sp[ir * 29 + j];
        #pragma unroll
        for (int oi = 0; oi < 5; ++oi) {
            int ki = ir - oi;
            if (ki < 0 || ki > 4) continue;
            #pragma unroll
            for (int oj = 0; oj < 5; ++oj)
                #pragma unroll
                for (int kj = 0; kj < 5; ++kj)
                    acc[oi][oj] = fmaf(row[oj + kj], kk[ki * 5 + kj], acc[oi][oj]);
        }
    }
    float* op = out + (size_t)(bc0 + lb) * 625;
    #pragma unroll
    for (int oi = 0; oi < 5; ++oi)
        #pragma unroll
        for (int oj = 0; oj < 5; ++oj)
            op[(ohg * 5 + oi) * 25 + owg * 5 + oj] = acc[oi][oj];
}

// ---------------------------------------------------------------------------
// Fallback (round-1 fp32 path) in case ws_size is too small
// ---------------------------------------------------------------------------
template<int IN_H>
__global__ __launch_bounds__(256)
void branch_fallback(const float* __restrict__ in, const float* __restrict__ dw_w,
                     const float* __restrict__ bn1, const float* __restrict__ pw_w,
                     const float* __restrict__ pw_b, const float* __restrict__ bn2,
                     float* __restrict__ out) {
    constexpr int OUT_H = IN_H - 2;
    constexpr int P = OUT_H * OUT_H;
    const int n0  = blockIdx.x * 64;
    const int co0 = blockIdx.y * 64;
    const int tid = threadIdx.x;
    const int tx = tid & 15, ty = tid >> 4;
    __shared__ __align__(16) float Ws[16][64];
    __shared__ __align__(16) float Xs2[16][64];
    float acc[4][4] = {};
    for (int k0 = 0; k0 < C; k0 += 16) {
        #pragma unroll
        for (int e = 0; e < 4; e++) {
            int idx = e * 256 + tid;
            int m = idx & 63, kk = idx >> 6;
            Ws[kk][m] = pw_w[(co0 + m) * C + (k0 + kk)];
        }
        #pragma unroll
        for (int e = 0; e < 4; e++) {
            int idx = e * 256 + tid;
            int nn = idx & 63, kk = idx >> 6;
            int ci = k0 + kk;
            int n = n0 + nn;
            int b = n / P, p = n - b * P;
            int oh = p / OUT_H, ow = p - oh * OUT_H;
            const float* ip = in + (((size_t)b * C + ci) * IN_H + oh) * IN_H + ow;
            const float* wp = dw_w + ci * 9;
            float s = 0.f;
            #pragma unroll
            for (int dy = 0; dy < 3; dy++)
                #pragma unroll
                for (int dx = 0; dx < 3; dx++)
                    s = fmaf(ip[dy * IN_H + dx], wp[dy * 3 + dx], s);
            float inv = bn1[ci] * rsqrtf(bn1[3 * C + ci] + EPS);
            float y = s * inv + (bn1[C + ci] - bn1[2 * C + ci] * inv);
            Xs2[kk][nn] = fminf(fmaxf(y, 0.f), 6.f);
        }
        __syncthreads();
        #pragma unroll
        for (int kk = 0; kk < 16; kk++) {
            float4 av = *reinterpret_cast<const float4*>(&Ws[kk][ty * 4]);
            float4 bv = *reinterpret_cast<const float4*>(&Xs2[kk][tx * 4]);
            float a[4] = {av.x, av.y, av.z, av.w};
            float bb[4] = {bv.x, bv.y, bv.z, bv.w};
            #pragma unroll
            for (int i = 0; i < 4; i++)
                #pragma unroll
                for (int j = 0; j < 4; j++)
                    acc[i][j] = fmaf(a[i], bb[j], acc[i][j]);
        }
        __syncthreads();
    }
    #pragma unroll
    for (int i = 0; i < 4; i++) {
        int co = co0 + ty * 4 + i;
        float inv = bn2[co] * rsqrtf(bn2[3 * C + co] + EPS);
        float sh  = (bn2[C + co] - bn2[2 * C + co] * inv) + pw_b[co] * inv;
        int n = n0 + tx * 4;
        #pragma unroll
        for (int j = 0; j < 4; j++) {
            int nj = n + j;
            int bj2 = nj / P, pj2 = nj - bj2 * P;
            out[((size_t)bj2 * C + co) * P + pj2] = acc[i][j] * inv + sh;
        }
    }
}

extern "C" void kernel_launch(void* const* d_in, const int* in_sizes, int n_in,
                              void* d_out, int out_size, void* d_ws, size_t ws_size,
                              hipStream_t stream) {
    const float* kernel = (const float*)d_in[0];
    const float* search = (const float*)d_in[1];
    const float* k_dw_w = (const float*)d_in[2];
    const float* k_bn1  = (const float*)d_in[3];
    const float* k_pw_w = (const float*)d_in[4];
    const float* k_pw_b = (const float*)d_in[5];
    const float* k_bn2  = (const float*)d_in[6];
    const float* s_dw_w = (const float*)d_in[7];
    const float* s_bn1  = (const float*)d_in[8];
    const float* s_pw_w = (const float*)d_in[9];
    const float* s_pw_b = (const float*)d_in[10];
    const float* s_bn2  = (const float*)d_in[11];

    constexpr size_t SB_B  = (size_t)NSG * C * 4;      // 110,231,552
    constexpr size_t KB_B  = (size_t)NKG * C * 4;      //   3,276,800
    constexpr size_t X3S_B = (size_t)NSG * 512;        //  55,115,776 per plane
    constexpr size_t X3K_B = (size_t)NKG * 512;        //   1,638,400 per plane
    constexpr size_t W_B   = (size_t)131072 * 2;       //     262,144 (hi+lo frag-major)
    constexpr size_t NEED  = SB_B + KB_B + 2 * X3S_B + 2 * X3K_B + 2 * W_B;

    if (ws_size >= NEED) {
        char* base = (char*)d_ws;
        float* Sb  = (float*)base;  base += SB_B;
        float* Kb  = (float*)base;  base += KB_B;
        u16* X3hs  = (u16*)base;    base += X3S_B;
        u16* X3ls  = (u16*)base;    base += X3S_B;
        u16* X3hk  = (u16*)base;    base += X3K_B;
        u16* X3lk  = (u16*)base;    base += X3K_B;
        u16* WtS   = (u16*)base;    base += W_B;
        u16* WtK   = (u16*)base;

        wprep2<<<dim3(256), dim3(256), 0, stream>>>(s_pw_w, k_pw_w, WtS, WtK);
        dw_pass3<31, 8><<<dim3(B, 32), dim3(256), 0, stream>>>(search, s_dw_w, s_bn1, X3hs, X3ls);
        dw_pass3<7, 32><<<dim3(B, 8), dim3(256), 0, stream>>>(kernel, k_dw_w, k_bn1, X3hk, X3lk);
        gemm4<841><<<dim3(NSG / 64), dim3(256), 0, stream>>>(X3hs, X3ls, WtS, s_pw_b, s_bn2, Sb);
        gemm4<25><<<dim3(NKG / 64), dim3(256), 0, stream>>>(X3hk, X3lk, WtK, k_pw_b, k_bn2, Kb);
        xcorr2<<<dim3((B * C + 9) / 10), dim3(256), 0, stream>>>(Sb, Kb, (float*)d_out);
    } else {
        float* s_buf = (float*)d_ws;
        float* k_buf = s_buf + (size_t)B * C * 29 * 29;
        branch_fallback<7><<<dim3(50, 4), dim3(256), 0, stream>>>(
            kernel, k_dw_w, k_bn1, k_pw_w, k_pw_b, k_bn2, k_buf);
        branch_fallback<31><<<dim3(1682, 4), dim3(256), 0, stream>>>(
            search, s_dw_w, s_bn1, s_pw_w, s_pw_b, s_bn2, s_buf);
        xcorr2<<<dim3((B * C + 9) / 10), dim3(256), 0, stream>>>(s_buf, k_buf, (float*)d_out);
    }
}